// Round 5
// baseline (485.241 us; speedup 1.0000x reference)
//
#include <hip/hip_runtime.h>
#include <math.h>

typedef __attribute__((ext_vector_type(8))) short short8v;   // 8 bf16 (4 VGPR)
typedef __attribute__((ext_vector_type(4))) float f32x4;
typedef __attribute__((ext_vector_type(2))) float f32x2;

// ---------------- helpers ----------------
__device__ __forceinline__ unsigned short f2bf(float f) {
    union { float f; unsigned int u; } v; v.f = f;
    unsigned int r = v.u + 0x7FFFu + ((v.u >> 16) & 1u);
    return (unsigned short)(r >> 16);
}
__device__ __forceinline__ float bflo(unsigned int v) {
    union { unsigned int u; float f; } x; x.u = v << 16; return x.f;
}
__device__ __forceinline__ float bfhi(unsigned int v) {
    union { unsigned int u; float f; } x; x.u = v & 0xFFFF0000u; return x.f;
}
__device__ __forceinline__ unsigned char f2fp8(float f) {
    return (unsigned char)(__builtin_amdgcn_cvt_pk_fp8_f32(f, f, 0, false) & 0xFF);
}

// ---------------- CSR build ----------------
__global__ void hist_kernel(const int* __restrict__ dst, int* __restrict__ deg, int E) {
    int e = blockIdx.x * 256 + threadIdx.x;
    if (e < E) atomicAdd(&deg[dst[e]], 1);
}

__global__ __launch_bounds__(1024) void scan_kernel(const int* __restrict__ deg,
                                                    int* __restrict__ rowptr, int N, int E) {
    __shared__ int sm[16];
    __shared__ int stot;
    const int lane = threadIdx.x & 63, wid = threadIdx.x >> 6;
    int carry = 0;
    for (int base = 0; base < N; base += 8192) {
        int i0 = base + (int)threadIdx.x * 8;
        int ex[8];
        int run = 0;
#pragma unroll
        for (int t = 0; t < 8; ++t) {
            int i = i0 + t;
            int v = (i < N) ? deg[i] : 0;
            ex[t] = run;
            run += v;
        }
        int val = run;
#pragma unroll
        for (int off = 1; off < 64; off <<= 1) {
            int t2 = __shfl_up(val, off, 64);
            if (lane >= off) val += t2;
        }
        if (lane == 63) sm[wid] = val;
        __syncthreads();
        if (threadIdx.x == 0) {
            int rr = 0;
#pragma unroll
            for (int w2 = 0; w2 < 16; ++w2) { rr += sm[w2]; sm[w2] = rr; }
            stot = rr;
        }
        __syncthreads();
        int wpre = (wid > 0) ? sm[wid - 1] : 0;
        int excl = wpre + val - run;
#pragma unroll
        for (int t = 0; t < 8; ++t) {
            int i = i0 + t;
            if (i < N) rowptr[i] = carry + excl + ex[t];
        }
        carry += stot;
        __syncthreads();
    }
    if (threadIdx.x == 0) rowptr[N] = E;
}

// scatter also materializes src-ids and aux in CSR order (kills indirection in hot loops)
__global__ void scatter_kernel(const int* __restrict__ src, const int* __restrict__ dst,
                               const float* __restrict__ aux,
                               const int* __restrict__ rowptr, int* __restrict__ cursor,
                               int* __restrict__ csr_e, int* __restrict__ csr_src,
                               float2* __restrict__ aux2, int E) {
    int e = blockIdx.x * 256 + threadIdx.x;
    if (e < E) {
        int d = dst[e];
        int pos = rowptr[d] + atomicAdd(&cursor[d], 1);
        csr_e[pos] = e;
        csr_src[pos] = src[e];
        aux2[pos] = *(const float2*)(aux + 2 * e);
    }
}

// deterministic order: sort each node's list by edge id (small degrees ~12)
__global__ void sort_kernel(int* __restrict__ csr_e, int* __restrict__ csr_src,
                            float2* __restrict__ aux2, const int* __restrict__ rowptr, int N) {
    int v = blockIdx.x * 256 + threadIdx.x;
    if (v >= N) return;
    int s = rowptr[v], e = rowptr[v + 1];
    for (int i = s + 1; i < e; ++i) {
        int key = csr_e[i];
        int ks = csr_src[i];
        float2 ka = aux2[i];
        int j = i - 1;
        while (j >= s && csr_e[j] > key) {
            csr_e[j + 1] = csr_e[j];
            csr_src[j + 1] = csr_src[j];
            aux2[j + 1] = aux2[j];
            --j;
        }
        csr_e[j + 1] = key;
        csr_src[j + 1] = ks;
        aux2[j + 1] = ka;
    }
}

__global__ void bounds_kernel(const int* __restrict__ batch, int* __restrict__ gstart,
                              int* __restrict__ gend, int N) {
    int i = blockIdx.x * 256 + threadIdx.x;
    if (i >= N) return;
    int b = batch[i];
    if (i == 0 || batch[i - 1] != b) gstart[b] = i;
    if (i == N - 1 || batch[i + 1] != b) gend[b] = i + 1;
}

// ---------------- weight pack (6 matrices in one launch) ----------------
// Wp[((ks*8+ct)*64+l)*8+j] = bf16(W[ks*32+(l>>4)*8+j][ct*16+(l&15)])
__global__ __launch_bounds__(256) void pack6_kernel(const float* __restrict__ s0,
                                                    const float* __restrict__ s1,
                                                    const float* __restrict__ s2,
                                                    const float* __restrict__ s3,
                                                    const float* __restrict__ s4,
                                                    const float* __restrict__ s5,
                                                    unsigned short* __restrict__ Wp) {
    int which = blockIdx.x >> 6;
    const float* W = (which == 0) ? s0 : (which == 1) ? s1 : (which == 2) ? s2
                   : (which == 3) ? s3 : (which == 4) ? s4 : s5;
    int t = (blockIdx.x & 63) * 256 + threadIdx.x;
    int j = t & 7, l = (t >> 3) & 63, ct = (t >> 9) & 7, ks = t >> 12;
    int k = ks * 32 + (l >> 4) * 8 + j;
    int n = ct * 16 + (l & 15);
    Wp[which * 16384 + t] = f2bf(W[k * 128 + n]);
}

// ---------------- fused MFMA GEMM: xl = A@WL + b; P = xl@WP; Q = xl@WQ ----------------
// writes xl (f32), V (fp8 of xl), P (fp8), Q (bf16)
__global__ __launch_bounds__(256) void linpq_kernel(const float* __restrict__ A,
                                                    const unsigned short* __restrict__ WpL,
                                                    const float* __restrict__ bias,
                                                    const unsigned short* __restrict__ WpP,
                                                    const unsigned short* __restrict__ WpQ,
                                                    float* __restrict__ D,
                                                    unsigned char* __restrict__ Vf8,
                                                    unsigned char* __restrict__ Pf8,
                                                    unsigned short* __restrict__ Qbf, int M) {
    __shared__ unsigned short lds[32][136];  // +8 pad
    const int l = threadIdx.x & 63, w = threadIdx.x >> 6;
    const int tile = w >> 1, ch = w & 1;
    const int rowbase = blockIdx.x * 32 + tile * 16;
    const int r = rowbase + (l & 15);
    const int kc = (l >> 4) * 8;

    short8v afr[4];
    if (r < M) {
        const float* ap = A + (size_t)r * 128 + kc;
#pragma unroll
        for (int ks = 0; ks < 4; ++ks) {
            float4 x0 = *(const float4*)(ap + ks * 32);
            float4 x1 = *(const float4*)(ap + ks * 32 + 4);
            unsigned short u[8] = {f2bf(x0.x), f2bf(x0.y), f2bf(x0.z), f2bf(x0.w),
                                   f2bf(x1.x), f2bf(x1.y), f2bf(x1.z), f2bf(x1.w)};
            afr[ks] = *(short8v*)u;
        }
    } else {
#pragma unroll
        for (int ks = 0; ks < 4; ++ks)
#pragma unroll
            for (int j = 0; j < 8; ++j) afr[ks][j] = 0;
    }

    f32x4 acc[4];
#pragma unroll
    for (int c = 0; c < 4; ++c)
#pragma unroll
        for (int j = 0; j < 4; ++j) acc[c][j] = 0.f;

    const short8v* wl = (const short8v*)WpL;
#pragma unroll
    for (int ks = 0; ks < 4; ++ks)
#pragma unroll
        for (int c = 0; c < 4; ++c)
            acc[c] = __builtin_amdgcn_mfma_f32_16x16x32_bf16(
                afr[ks], wl[(ks * 8 + ch * 4 + c) * 64 + l], acc[c], 0, 0, 0);

    const int rb = rowbase + (l >> 4) * 4;
    const int lrb = tile * 16 + (l >> 4) * 4;
#pragma unroll
    for (int c = 0; c < 4; ++c) {
        int col = (ch * 4 + c) * 16 + (l & 15);
        float bv = bias ? bias[col] : 0.f;
#pragma unroll
        for (int j = 0; j < 4; ++j) {
            int row = rb + j;
            if (row < M) {
                float v = acc[c][j] + bv;
                unsigned short bf = f2bf(v);
                D[(size_t)row * 128 + col] = v;
                Vf8[(size_t)row * 128 + col] = f2fp8(v);
                lds[lrb + j][col] = bf;
            } else {
                lds[lrb + j][col] = 0;
            }
        }
    }
    __syncthreads();

    short8v xfr[4];
#pragma unroll
    for (int ks = 0; ks < 4; ++ks)
        xfr[ks] = *(const short8v*)&lds[tile * 16 + (l & 15)][kc + ks * 32];

    f32x4 accP[4], accQ[4];
#pragma unroll
    for (int c = 0; c < 4; ++c)
#pragma unroll
        for (int j = 0; j < 4; ++j) { accP[c][j] = 0.f; accQ[c][j] = 0.f; }

    const short8v* wp = (const short8v*)WpP;
    const short8v* wq = (const short8v*)WpQ;
#pragma unroll
    for (int ks = 0; ks < 4; ++ks)
#pragma unroll
        for (int c = 0; c < 4; ++c) {
            accP[c] = __builtin_amdgcn_mfma_f32_16x16x32_bf16(
                xfr[ks], wp[(ks * 8 + ch * 4 + c) * 64 + l], accP[c], 0, 0, 0);
            accQ[c] = __builtin_amdgcn_mfma_f32_16x16x32_bf16(
                xfr[ks], wq[(ks * 8 + ch * 4 + c) * 64 + l], accQ[c], 0, 0, 0);
        }

#pragma unroll
    for (int c = 0; c < 4; ++c) {
        int col = (ch * 4 + c) * 16 + (l & 15);
#pragma unroll
        for (int j = 0; j < 4; ++j) {
            int row = rb + j;
            if (row < M) {
                Pf8[(size_t)row * 128 + col] = f2fp8(accP[c][j]);
                Qbf[(size_t)row * 128 + col] = f2bf(accQ[c][j]);
            }
        }
    }
}

// ---------------- phase 1: edge logits + softmax sums (node-centric) ----------------
// 32 lanes/node (4 ch/lane), 2 nodes/wave, 8 nodes/block.
// wt[i] = exp(logit_i) (unnormalized); nodescale[v] = 1/(sum*deg).
// Logits bounded by Cauchy-Schwarz: |logit| <= sqrt(128)*||aw2|| ~ 7 -> exp safe w/o max shift.
__global__ __launch_bounds__(256) void attn_kernel(
    const unsigned char* __restrict__ Pf8, const unsigned short* __restrict__ Qbf,
    const int* __restrict__ csr_src, const float2* __restrict__ aux2,
    const int* __restrict__ rowptr,
    const float* __restrict__ wa0, const float* __restrict__ wa1,
    const float* __restrict__ ab1, const float* __restrict__ lng,
    const float* __restrict__ lnb, const float* __restrict__ aw2,
    const float* __restrict__ ab2,
    float* __restrict__ wt, float* __restrict__ nodescale, int N) {
    const int lane32 = threadIdx.x & 31;
    const int v = blockIdx.x * 8 + (threadIdx.x >> 5);
    if (v >= N) return;
    const int j = lane32 * 4;

    float w0[4], w1[4], b1c[4], lg_[4], lb_[4], w2[4];
    *(float4*)w0 = *(const float4*)(wa0 + j);
    *(float4*)w1 = *(const float4*)(wa1 + j);
    *(float4*)b1c = *(const float4*)(ab1 + j);
    *(float4*)lg_ = *(const float4*)(lng + j);
    *(float4*)lb_ = *(const float4*)(lnb + j);
    *(float4*)w2 = *(const float4*)(aw2 + j);
    const float ab2v = ab2[0];

    uint2 qv = *(const uint2*)(Qbf + (size_t)v * 128 + j);
    float q[4] = {bflo(qv.x), bfhi(qv.x), bflo(qv.y), bfhi(qv.y)};

    const int s0 = rowptr[v], s1e = rowptr[v + 1];
    const int deg = s1e - s0;
    float ssum = 0.f;

    unsigned int p0 = 0, p1 = 0;
    float2 x0 = make_float2(0.f, 0.f), x1 = x0;
#define GATH1(idx, PP, XX)                                              \
    if ((idx) < s1e) {                                                  \
        PP = *(const unsigned int*)(Pf8 + (size_t)csr_src[idx] * 128 + j); \
        XX = aux2[idx];                                                 \
    }
    GATH1(s0, p0, x0)
    GATH1(s0 + 1, p1, x1)

    for (int i = s0; i < s1e; i += 2) {
        unsigned int c0 = p0, c1 = p1;
        float2 d0 = x0, d1 = x1;
        const bool val1 = (i + 1 < s1e);
        GATH1(i + 2, p0, x0)
        GATH1(i + 3, p1, x1)

        f32x2 pa = __builtin_amdgcn_cvt_pk_f32_fp8((int)c0, false);
        f32x2 pb = __builtin_amdgcn_cvt_pk_f32_fp8((int)c0, true);
        f32x2 pc = __builtin_amdgcn_cvt_pk_f32_fp8((int)c1, false);
        f32x2 pd = __builtin_amdgcn_cvt_pk_f32_fp8((int)c1, true);
        float pv0[4] = {pa[0], pa[1], pb[0], pb[1]};
        float pv1[4] = {pc[0], pc[1], pd[0], pd[1]};

        float t0[4], t1[4];
        float r1 = 0.f, r2 = 0.f, r3 = 0.f, r4 = 0.f;
#pragma unroll
        for (int k = 0; k < 4; ++k) {
            t0[k] = pv0[k] + q[k] + d0.x * w0[k] + d0.y * w1[k] + b1c[k];
            t1[k] = pv1[k] + q[k] + d1.x * w0[k] + d1.y * w1[k] + b1c[k];
            r1 += t0[k]; r2 += t0[k] * t0[k];
            r3 += t1[k]; r4 += t1[k] * t1[k];
        }
#pragma unroll
        for (int mk = 16; mk >= 1; mk >>= 1) {
            r1 += __shfl_xor(r1, mk, 64);
            r2 += __shfl_xor(r2, mk, 64);
            r3 += __shfl_xor(r3, mk, 64);
            r4 += __shfl_xor(r4, mk, 64);
        }
        float mean0 = r1 * (1.f / 128.f);
        float rstd0 = rsqrtf(r2 * (1.f / 128.f) - mean0 * mean0 + 1e-5f);
        float mean1 = r3 * (1.f / 128.f);
        float rstd1 = rsqrtf(r4 * (1.f / 128.f) - mean1 * mean1 + 1e-5f);
        float dot0 = 0.f, dot1 = 0.f;
#pragma unroll
        for (int k = 0; k < 4; ++k) {
            float h0 = fmaxf((t0[k] - mean0) * rstd0 * lg_[k] + lb_[k], 0.f);
            float h1 = fmaxf((t1[k] - mean1) * rstd1 * lg_[k] + lb_[k], 0.f);
            dot0 += h0 * w2[k];
            dot1 += h1 * w2[k];
        }
#pragma unroll
        for (int mk = 16; mk >= 1; mk >>= 1) {
            dot0 += __shfl_xor(dot0, mk, 64);
            dot1 += __shfl_xor(dot1, mk, 64);
        }
        float we0 = __expf(dot0 + ab2v);
        float we1 = __expf(val1 ? (dot1 + ab2v) : -100.f);
        ssum += we0 + we1;
        if (lane32 == 0) {
            wt[i] = we0;
            if (val1) wt[i + 1] = we1;
        }
    }
#undef GATH1
    if (lane32 == 0) nodescale[v] = (deg > 0) ? 1.f / (ssum * (float)deg) : 0.f;
}

// ---------------- phase 2: weighted aggregation + residual + epilogue ----------------
// 16 lanes/node (8 ch/lane). Pure gather-FMA: no shuffles in the loop.
// MODE 0: out = relu(xl + acc*ns); MODE 1: out = LN(xl + acc*ns; g,b)
template <int MODE>
__global__ __launch_bounds__(256) void aggr_kernel(
    const float* __restrict__ xl, const unsigned char* __restrict__ Vf8,
    const float* __restrict__ wt, const float* __restrict__ nodescale,
    const int* __restrict__ csr_src, const int* __restrict__ rowptr,
    const float* __restrict__ g, const float* __restrict__ b,
    float* __restrict__ out, int N) {
    const int lane16 = threadIdx.x & 15;
    const int v = blockIdx.x * 16 + (threadIdx.x >> 4);
    if (v >= N) return;
    const int jb = lane16 * 8;

    const int s0 = rowptr[v], s1e = rowptr[v + 1];
    float acc[8] = {0.f, 0.f, 0.f, 0.f, 0.f, 0.f, 0.f, 0.f};

    uint2 v0 = make_uint2(0, 0), v1 = v0;
    float wb0 = 0.f, wb1 = 0.f;
#define GATH2(idx, VV, WW)                                     \
    if ((idx) < s1e) {                                         \
        VV = *(const uint2*)(Vf8 + (size_t)csr_src[idx] * 128 + jb); \
        WW = wt[idx];                                          \
    }
    GATH2(s0, v0, wb0)
    GATH2(s0 + 1, v1, wb1)

    for (int i = s0; i < s1e; i += 2) {
        uint2 c0 = v0, c1 = v1;
        float u0 = wb0;
        float u1 = (i + 1 < s1e) ? wb1 : 0.f;
        GATH2(i + 2, v0, wb0)
        GATH2(i + 3, v1, wb1)

        f32x2 a0 = __builtin_amdgcn_cvt_pk_f32_fp8((int)c0.x, false);
        f32x2 a1 = __builtin_amdgcn_cvt_pk_f32_fp8((int)c0.x, true);
        f32x2 a2 = __builtin_amdgcn_cvt_pk_f32_fp8((int)c0.y, false);
        f32x2 a3 = __builtin_amdgcn_cvt_pk_f32_fp8((int)c0.y, true);
        f32x2 b0 = __builtin_amdgcn_cvt_pk_f32_fp8((int)c1.x, false);
        f32x2 b1 = __builtin_amdgcn_cvt_pk_f32_fp8((int)c1.x, true);
        f32x2 b2 = __builtin_amdgcn_cvt_pk_f32_fp8((int)c1.y, false);
        f32x2 b3 = __builtin_amdgcn_cvt_pk_f32_fp8((int)c1.y, true);
        acc[0] += u0 * a0[0] + u1 * b0[0];
        acc[1] += u0 * a0[1] + u1 * b0[1];
        acc[2] += u0 * a1[0] + u1 * b1[0];
        acc[3] += u0 * a1[1] + u1 * b1[1];
        acc[4] += u0 * a2[0] + u1 * b2[0];
        acc[5] += u0 * a2[1] + u1 * b2[1];
        acc[6] += u0 * a3[0] + u1 * b3[0];
        acc[7] += u0 * a3[1] + u1 * b3[1];
    }
#undef GATH2

    const float ns = nodescale[v];
    float4 xa = *(const float4*)(xl + (size_t)v * 128 + jb);
    float4 xb = *(const float4*)(xl + (size_t)v * 128 + jb + 4);
    float o[8];
    o[0] = xa.x + acc[0] * ns; o[1] = xa.y + acc[1] * ns;
    o[2] = xa.z + acc[2] * ns; o[3] = xa.w + acc[3] * ns;
    o[4] = xb.x + acc[4] * ns; o[5] = xb.y + acc[5] * ns;
    o[6] = xb.z + acc[6] * ns; o[7] = xb.w + acc[7] * ns;

    float* op = out + (size_t)v * 128 + jb;
    if (MODE == 0) {
        float4 r0, r1v;
        r0.x = fmaxf(o[0], 0.f); r0.y = fmaxf(o[1], 0.f);
        r0.z = fmaxf(o[2], 0.f); r0.w = fmaxf(o[3], 0.f);
        r1v.x = fmaxf(o[4], 0.f); r1v.y = fmaxf(o[5], 0.f);
        r1v.z = fmaxf(o[6], 0.f); r1v.w = fmaxf(o[7], 0.f);
        *(float4*)op = r0;
        *(float4*)(op + 4) = r1v;
    } else {
        float r1 = 0.f, r2 = 0.f;
#pragma unroll
        for (int k = 0; k < 8; ++k) { r1 += o[k]; r2 += o[k] * o[k]; }
#pragma unroll
        for (int mk = 8; mk >= 1; mk >>= 1) {
            r1 += __shfl_xor(r1, mk, 64);
            r2 += __shfl_xor(r2, mk, 64);
        }
        float mean = r1 * (1.f / 128.f);
        float rstd = rsqrtf(r2 * (1.f / 128.f) - mean * mean + 1e-5f);
        float gg[8], bb[8];
        *(float4*)(gg) = *(const float4*)(g + jb);
        *(float4*)(gg + 4) = *(const float4*)(g + jb + 4);
        *(float4*)(bb) = *(const float4*)(b + jb);
        *(float4*)(bb + 4) = *(const float4*)(b + jb + 4);
        float4 r0, r1v;
        r0.x = (o[0] - mean) * rstd * gg[0] + bb[0];
        r0.y = (o[1] - mean) * rstd * gg[1] + bb[1];
        r0.z = (o[2] - mean) * rstd * gg[2] + bb[2];
        r0.w = (o[3] - mean) * rstd * gg[3] + bb[3];
        r1v.x = (o[4] - mean) * rstd * gg[4] + bb[4];
        r1v.y = (o[5] - mean) * rstd * gg[5] + bb[5];
        r1v.z = (o[6] - mean) * rstd * gg[6] + bb[6];
        r1v.w = (o[7] - mean) * rstd * gg[7] + bb[7];
        *(float4*)op = r0;
        *(float4*)(op + 4) = r1v;
    }
}

// ---------------- pool stage 1: per-(graph, slice) partial max ----------------
__global__ __launch_bounds__(128) void pool1_kernel(const float* __restrict__ h,
                                                    const int* __restrict__ gstart,
                                                    const int* __restrict__ gend,
                                                    float* __restrict__ part) {
    int gph = blockIdx.x >> 4;
    int sl = blockIdx.x & 15;
    int col = threadIdx.x;
    int s = gstart[gph], e = gend[gph];
    float m = -INFINITY;
    for (int r = s + sl; r < e; r += 16) m = fmaxf(m, h[(size_t)r * 128 + col]);
    part[(size_t)blockIdx.x * 128 + col] = m;
}

// ---------------- classifier head (folds pool stage 2) ----------------
__global__ __launch_bounds__(128) void cls_kernel(const float* __restrict__ part,
                                                  const float* __restrict__ cw,
                                                  const float* __restrict__ cb,
                                                  float* __restrict__ out) {
    int gph = blockIdx.x, c = threadIdx.x;
    float m = -INFINITY;
#pragma unroll
    for (int sl = 0; sl < 16; ++sl) m = fmaxf(m, part[(size_t)(gph * 16 + sl) * 128 + c]);
    __shared__ float f[128];
    f[c] = m;
    __syncthreads();
    float acc = cb[c];
#pragma unroll 8
    for (int k = 0; k < 128; ++k) acc += f[k] * cw[k * 128 + c];
    out[gph * 128 + c] = acc;
}

// ---------------- launch ----------------
extern "C" void kernel_launch(void* const* d_in, const int* in_sizes, int n_in,
                              void* d_out, int out_size, void* d_ws, size_t ws_size,
                              hipStream_t stream) {
    const float* x      = (const float*)d_in[0];
    const int*   ei     = (const int*)d_in[1];
    const float* aux    = (const float*)d_in[2];
    const int*   batch  = (const int*)d_in[3];
    const float* w_lin1 = (const float*)d_in[4];
    const float* b_lin1 = (const float*)d_in[5];
    const float* aw1_1  = (const float*)d_in[6];
    const float* ab1_1  = (const float*)d_in[7];
    const float* lng1   = (const float*)d_in[8];
    const float* lnb1   = (const float*)d_in[9];
    const float* aw2_1  = (const float*)d_in[10];
    const float* ab2_1  = (const float*)d_in[11];
    const float* w_lin2 = (const float*)d_in[12];
    const float* b_lin2 = (const float*)d_in[13];
    const float* aw1_2  = (const float*)d_in[14];
    const float* ab1_2  = (const float*)d_in[15];
    const float* lng2   = (const float*)d_in[16];
    const float* lnb2   = (const float*)d_in[17];
    const float* aw2_2  = (const float*)d_in[18];
    const float* ab2_2  = (const float*)d_in[19];
    const float* cls_w  = (const float*)d_in[20];
    const float* cls_b  = (const float*)d_in[21];
    const float* norm_g = (const float*)d_in[22];
    const float* norm_b = (const float*)d_in[23];

    const int N = in_sizes[0] / 128;
    const int E = in_sizes[2] / 2;
    const int G = 64;
    const int* src = ei;
    const int* dst = ei + E;

    // workspace layout (f32/int region, then bf16, then fp8)
    float*          xl        = (float*)d_ws;                          // N*128
    float*          wt        = xl + (size_t)N * 128;                  // E
    float*          nodescale = wt + E;                                // N
    float2*         aux2      = (float2*)(nodescale + N);              // E
    int*            deg       = (int*)(aux2 + E);                      // N
    int*            cursor    = deg + N;                               // N
    int*            rowptr    = cursor + N;                            // N+1
    int*            csr_e     = rowptr + N + 1;                        // E
    int*            csr_src   = csr_e + E;                             // E
    int*            gstart    = csr_src + E;                           // G
    int*            gend      = gstart + G;                            // G
    float*          part      = (float*)(gend + G);                    // 1024*128
    unsigned short* Qbf       = (unsigned short*)(part + 1024 * 128);  // N*128
    unsigned short* wpack     = Qbf + (size_t)N * 128;                 // 6*16384
    unsigned char*  Pf8       = (unsigned char*)(wpack + 6 * 16384);   // N*128
    unsigned char*  Vf8       = Pf8 + (size_t)N * 128;                 // N*128

    unsigned short* wp_lin1 = wpack;
    unsigned short* wp_s1   = wpack + 16384;
    unsigned short* wp_d1   = wpack + 2 * 16384;
    unsigned short* wp_lin2 = wpack + 3 * 16384;
    unsigned short* wp_s2   = wpack + 4 * 16384;
    unsigned short* wp_d2   = wpack + 5 * 16384;

    float* hout   = (float*)d_out;
    float* clsout = hout + (size_t)N * 128;

    hipMemsetAsync(deg, 0, (size_t)(2 * N) * sizeof(int), stream);      // deg + cursor
    hipMemsetAsync(gstart, 0, (size_t)(2 * G) * sizeof(int), stream);

    const int eb = (E + 255) / 256;
    const int nb = (N + 255) / 256;
    const int lb = (N + 31) / 32;
    const int ab = (N + 7) / 8;
    const int gb2 = (N + 15) / 16;

    hist_kernel<<<eb, 256, 0, stream>>>(dst, deg, E);
    scan_kernel<<<1, 1024, 0, stream>>>(deg, rowptr, N, E);
    scatter_kernel<<<eb, 256, 0, stream>>>(src, dst, aux, rowptr, cursor,
                                           csr_e, csr_src, aux2, E);
    sort_kernel<<<nb, 256, 0, stream>>>(csr_e, csr_src, aux2, rowptr, N);
    bounds_kernel<<<nb, 256, 0, stream>>>(batch, gstart, gend, N);

    pack6_kernel<<<384, 256, 0, stream>>>(w_lin1, aw1_1, aw1_1 + 128 * 128,
                                          w_lin2, aw1_2, aw1_2 + 128 * 128, wpack);

    // ---- conv1 ----
    linpq_kernel<<<lb, 256, 0, stream>>>(x, wp_lin1, b_lin1, wp_s1, wp_d1,
                                         xl, Vf8, Pf8, Qbf, N);
    attn_kernel<<<ab, 256, 0, stream>>>(Pf8, Qbf, csr_src, aux2, rowptr,
                                        aw1_1 + 256 * 128, aw1_1 + 257 * 128,
                                        ab1_1, lng1, lnb1, aw2_1, ab2_1,
                                        wt, nodescale, N);
    aggr_kernel<0><<<gb2, 256, 0, stream>>>(xl, Vf8, wt, nodescale, csr_src, rowptr,
                                            nullptr, nullptr, hout, N);
    // ---- conv2 ----
    linpq_kernel<<<lb, 256, 0, stream>>>(hout, wp_lin2, b_lin2, wp_s2, wp_d2,
                                         xl, Vf8, Pf8, Qbf, N);
    attn_kernel<<<ab, 256, 0, stream>>>(Pf8, Qbf, csr_src, aux2, rowptr,
                                        aw1_2 + 256 * 128, aw1_2 + 257 * 128,
                                        ab1_2, lng2, lnb2, aw2_2, ab2_2,
                                        wt, nodescale, N);
    aggr_kernel<1><<<gb2, 256, 0, stream>>>(xl, Vf8, wt, nodescale, csr_src, rowptr,
                                            norm_g, norm_b, hout, N);
    // ---- head ----
    pool1_kernel<<<G * 16, 128, 0, stream>>>(hout, gstart, gend, part);
    cls_kernel<<<G, 128, 0, stream>>>(part, cls_w, cls_b, clsout);
}

// Round 6
// 363.142 us; speedup vs baseline: 1.3362x; 1.3362x over previous
//
#include <hip/hip_runtime.h>
#include <math.h>

typedef __attribute__((ext_vector_type(8))) short short8v;   // 8 bf16 (4 VGPR)
typedef __attribute__((ext_vector_type(4))) float f32x4;
typedef __attribute__((ext_vector_type(2))) float f32x2;

// ---------------- helpers ----------------
__device__ __forceinline__ unsigned short f2bf(float f) {
    union { float f; unsigned int u; } v; v.f = f;
    unsigned int r = v.u + 0x7FFFu + ((v.u >> 16) & 1u);
    return (unsigned short)(r >> 16);
}
__device__ __forceinline__ float bflo(unsigned int v) {
    union { unsigned int u; float f; } x; x.u = v << 16; return x.f;
}
__device__ __forceinline__ float bfhi(unsigned int v) {
    union { unsigned int u; float f; } x; x.u = v & 0xFFFF0000u; return x.f;
}
__device__ __forceinline__ unsigned char f2fp8(float f) {
    return (unsigned char)(__builtin_amdgcn_cvt_pk_fp8_f32(f, f, 0, false) & 0xFF);
}

// ---------------- CSR build ----------------
__global__ void hist_kernel(const int* __restrict__ dst, int* __restrict__ deg, int E) {
    int e = blockIdx.x * 256 + threadIdx.x;
    if (e < E) atomicAdd(&deg[dst[e]], 1);
}

__global__ __launch_bounds__(1024) void scan_kernel(const int* __restrict__ deg,
                                                    int* __restrict__ rowptr, int N, int E) {
    __shared__ int sm[16];
    __shared__ int stot;
    const int lane = threadIdx.x & 63, wid = threadIdx.x >> 6;
    int carry = 0;
    for (int base = 0; base < N; base += 8192) {
        int i0 = base + (int)threadIdx.x * 8;
        int ex[8];
        int run = 0;
#pragma unroll
        for (int t = 0; t < 8; ++t) {
            int i = i0 + t;
            int v = (i < N) ? deg[i] : 0;
            ex[t] = run;
            run += v;
        }
        int val = run;
#pragma unroll
        for (int off = 1; off < 64; off <<= 1) {
            int t2 = __shfl_up(val, off, 64);
            if (lane >= off) val += t2;
        }
        if (lane == 63) sm[wid] = val;
        __syncthreads();
        if (threadIdx.x == 0) {
            int rr = 0;
#pragma unroll
            for (int w2 = 0; w2 < 16; ++w2) { rr += sm[w2]; sm[w2] = rr; }
            stot = rr;
        }
        __syncthreads();
        int wpre = (wid > 0) ? sm[wid - 1] : 0;
        int excl = wpre + val - run;
#pragma unroll
        for (int t = 0; t < 8; ++t) {
            int i = i0 + t;
            if (i < N) rowptr[i] = carry + excl + ex[t];
        }
        carry += stot;
        __syncthreads();
    }
    if (threadIdx.x == 0) rowptr[N] = E;
}

// scatter also materializes src, dst, aux in CSR order
__global__ void scatter_kernel(const int* __restrict__ src, const int* __restrict__ dst,
                               const float* __restrict__ aux,
                               const int* __restrict__ rowptr, int* __restrict__ cursor,
                               int* __restrict__ csr_e, int* __restrict__ csr_src,
                               int* __restrict__ csr_dst, float2* __restrict__ aux2, int E) {
    int e = blockIdx.x * 256 + threadIdx.x;
    if (e < E) {
        int d = dst[e];
        int pos = rowptr[d] + atomicAdd(&cursor[d], 1);
        csr_e[pos] = e;
        csr_src[pos] = src[e];
        csr_dst[pos] = d;
        aux2[pos] = *(const float2*)(aux + 2 * e);
    }
}

// deterministic order: sort each node's list by edge id (dst uniform per segment)
__global__ void sort_kernel(int* __restrict__ csr_e, int* __restrict__ csr_src,
                            float2* __restrict__ aux2, const int* __restrict__ rowptr, int N) {
    int v = blockIdx.x * 256 + threadIdx.x;
    if (v >= N) return;
    int s = rowptr[v], e = rowptr[v + 1];
    for (int i = s + 1; i < e; ++i) {
        int key = csr_e[i];
        int ks = csr_src[i];
        float2 ka = aux2[i];
        int j = i - 1;
        while (j >= s && csr_e[j] > key) {
            csr_e[j + 1] = csr_e[j];
            csr_src[j + 1] = csr_src[j];
            aux2[j + 1] = aux2[j];
            --j;
        }
        csr_e[j + 1] = key;
        csr_src[j + 1] = ks;
        aux2[j + 1] = ka;
    }
}

__global__ void bounds_kernel(const int* __restrict__ batch, int* __restrict__ gstart,
                              int* __restrict__ gend, int N) {
    int i = blockIdx.x * 256 + threadIdx.x;
    if (i >= N) return;
    int b = batch[i];
    if (i == 0 || batch[i - 1] != b) gstart[b] = i;
    if (i == N - 1 || batch[i + 1] != b) gend[b] = i + 1;
}

// ---------------- weight pack (6 matrices in one launch) ----------------
__global__ __launch_bounds__(256) void pack6_kernel(const float* __restrict__ s0,
                                                    const float* __restrict__ s1,
                                                    const float* __restrict__ s2,
                                                    const float* __restrict__ s3,
                                                    const float* __restrict__ s4,
                                                    const float* __restrict__ s5,
                                                    unsigned short* __restrict__ Wp) {
    int which = blockIdx.x >> 6;
    const float* W = (which == 0) ? s0 : (which == 1) ? s1 : (which == 2) ? s2
                   : (which == 3) ? s3 : (which == 4) ? s4 : s5;
    int t = (blockIdx.x & 63) * 256 + threadIdx.x;
    int j = t & 7, l = (t >> 3) & 63, ct = (t >> 9) & 7, ks = t >> 12;
    int k = ks * 32 + (l >> 4) * 8 + j;
    int n = ct * 16 + (l & 15);
    Wp[which * 16384 + t] = f2bf(W[k * 128 + n]);
}

// ---------------- fused MFMA GEMM: xl = A@WL + b; P = xl@WP; Q = xl@WQ ----------------
__global__ __launch_bounds__(256) void linpq_kernel(const float* __restrict__ A,
                                                    const unsigned short* __restrict__ WpL,
                                                    const float* __restrict__ bias,
                                                    const unsigned short* __restrict__ WpP,
                                                    const unsigned short* __restrict__ WpQ,
                                                    float* __restrict__ D,
                                                    unsigned char* __restrict__ Vf8,
                                                    unsigned char* __restrict__ Pf8,
                                                    unsigned short* __restrict__ Qbf, int M) {
    __shared__ unsigned short lds[32][136];  // +8 pad
    const int l = threadIdx.x & 63, w = threadIdx.x >> 6;
    const int tile = w >> 1, ch = w & 1;
    const int rowbase = blockIdx.x * 32 + tile * 16;
    const int r = rowbase + (l & 15);
    const int kc = (l >> 4) * 8;

    short8v afr[4];
    if (r < M) {
        const float* ap = A + (size_t)r * 128 + kc;
#pragma unroll
        for (int ks = 0; ks < 4; ++ks) {
            float4 x0 = *(const float4*)(ap + ks * 32);
            float4 x1 = *(const float4*)(ap + ks * 32 + 4);
            unsigned short u[8] = {f2bf(x0.x), f2bf(x0.y), f2bf(x0.z), f2bf(x0.w),
                                   f2bf(x1.x), f2bf(x1.y), f2bf(x1.z), f2bf(x1.w)};
            afr[ks] = *(short8v*)u;
        }
    } else {
#pragma unroll
        for (int ks = 0; ks < 4; ++ks)
#pragma unroll
            for (int j = 0; j < 8; ++j) afr[ks][j] = 0;
    }

    f32x4 acc[4];
#pragma unroll
    for (int c = 0; c < 4; ++c)
#pragma unroll
        for (int j = 0; j < 4; ++j) acc[c][j] = 0.f;

    const short8v* wl = (const short8v*)WpL;
#pragma unroll
    for (int ks = 0; ks < 4; ++ks)
#pragma unroll
        for (int c = 0; c < 4; ++c)
            acc[c] = __builtin_amdgcn_mfma_f32_16x16x32_bf16(
                afr[ks], wl[(ks * 8 + ch * 4 + c) * 64 + l], acc[c], 0, 0, 0);

    const int rb = rowbase + (l >> 4) * 4;
    const int lrb = tile * 16 + (l >> 4) * 4;
#pragma unroll
    for (int c = 0; c < 4; ++c) {
        int col = (ch * 4 + c) * 16 + (l & 15);
        float bv = bias ? bias[col] : 0.f;
#pragma unroll
        for (int j = 0; j < 4; ++j) {
            int row = rb + j;
            if (row < M) {
                float v = acc[c][j] + bv;
                unsigned short bf = f2bf(v);
                D[(size_t)row * 128 + col] = v;
                Vf8[(size_t)row * 128 + col] = f2fp8(v);
                lds[lrb + j][col] = bf;
            } else {
                lds[lrb + j][col] = 0;
            }
        }
    }
    __syncthreads();

    short8v xfr[4];
#pragma unroll
    for (int ks = 0; ks < 4; ++ks)
        xfr[ks] = *(const short8v*)&lds[tile * 16 + (l & 15)][kc + ks * 32];

    f32x4 accP[4], accQ[4];
#pragma unroll
    for (int c = 0; c < 4; ++c)
#pragma unroll
        for (int j = 0; j < 4; ++j) { accP[c][j] = 0.f; accQ[c][j] = 0.f; }

    const short8v* wp = (const short8v*)WpP;
    const short8v* wq = (const short8v*)WpQ;
#pragma unroll
    for (int ks = 0; ks < 4; ++ks)
#pragma unroll
        for (int c = 0; c < 4; ++c) {
            accP[c] = __builtin_amdgcn_mfma_f32_16x16x32_bf16(
                xfr[ks], wp[(ks * 8 + ch * 4 + c) * 64 + l], accP[c], 0, 0, 0);
            accQ[c] = __builtin_amdgcn_mfma_f32_16x16x32_bf16(
                xfr[ks], wq[(ks * 8 + ch * 4 + c) * 64 + l], accQ[c], 0, 0, 0);
        }

#pragma unroll
    for (int c = 0; c < 4; ++c) {
        int col = (ch * 4 + c) * 16 + (l & 15);
#pragma unroll
        for (int j = 0; j < 4; ++j) {
            int row = rb + j;
            if (row < M) {
                Pf8[(size_t)row * 128 + col] = f2fp8(accP[c][j]);
                Qbf[(size_t)row * 128 + col] = f2bf(accQ[c][j]);
            }
        }
    }
}

// ---------------- edge-parallel logits: 2 lanes/edge, 64 ch/lane ----------------
// wt[slot] = exp(logit) (unnormalized). No per-node loop, no atomics: aggr sums wt.
__global__ __launch_bounds__(256, 4) void attn_edge_kernel(
    const unsigned char* __restrict__ Pf8, const unsigned short* __restrict__ Qbf,
    const int* __restrict__ csr_src, const int* __restrict__ csr_dst,
    const float2* __restrict__ aux2,
    const float* __restrict__ wa0, const float* __restrict__ wa1,
    const float* __restrict__ ab1, const float* __restrict__ lng,
    const float* __restrict__ lnb, const float* __restrict__ aw2,
    const float* __restrict__ ab2,
    float* __restrict__ wt, int E) {
    __shared__ float lw[6][128];
    if (threadIdx.x < 128) {
        int c = threadIdx.x;
        lw[0][c] = wa0[c]; lw[1][c] = wa1[c]; lw[2][c] = ab1[c];
        lw[3][c] = lng[c]; lw[4][c] = lnb[c]; lw[5][c] = aw2[c];
    }
    __syncthreads();
    const int slot = blockIdx.x * 128 + ((int)threadIdx.x >> 1);
    if (slot >= E) return;
    const int co = (threadIdx.x & 1) << 6;  // channel offset: 0 or 64

    const int sn = csr_src[slot];
    const int dn = csr_dst[slot];
    const float2 a = aux2[slot];

    const uint4* prow = (const uint4*)(Pf8 + (size_t)sn * 128 + co);
    const uint4* qrow = (const uint4*)(Qbf + ((size_t)dn * 128 + co));

    float r1 = 0.f, r2 = 0.f;
    unsigned tp[32];  // 64 ch as packed bf16

#pragma unroll
    for (int g = 0; g < 4; ++g) {  // 16 channels per group
        uint4 pv = prow[g];
        uint4 qa = qrow[2 * g];
        uint4 qb = qrow[2 * g + 1];
        unsigned pwa[4] = {pv.x, pv.y, pv.z, pv.w};
        unsigned qwa[8] = {qa.x, qa.y, qa.z, qa.w, qb.x, qb.y, qb.z, qb.w};
#pragma unroll
        for (int cc = 0; cc < 4; ++cc) {  // 4 channels
            const int c = g * 4 + cc;
            f32x2 plo = __builtin_amdgcn_cvt_pk_f32_fp8((int)pwa[cc], false);
            f32x2 phi = __builtin_amdgcn_cvt_pk_f32_fp8((int)pwa[cc], true);
            float4 w0v = *(const float4*)&lw[0][co + 4 * c];
            float4 w1v = *(const float4*)&lw[1][co + 4 * c];
            float4 b1v = *(const float4*)&lw[2][co + 4 * c];
            float q0 = bflo(qwa[2 * cc]), q1 = bfhi(qwa[2 * cc]);
            float q2 = bflo(qwa[2 * cc + 1]), q3 = bfhi(qwa[2 * cc + 1]);
            float t0 = plo[0] + q0 + a.x * w0v.x + a.y * w1v.x + b1v.x;
            float t1 = plo[1] + q1 + a.x * w0v.y + a.y * w1v.y + b1v.y;
            float t2 = phi[0] + q2 + a.x * w0v.z + a.y * w1v.z + b1v.z;
            float t3 = phi[1] + q3 + a.x * w0v.w + a.y * w1v.w + b1v.w;
            r1 += (t0 + t1) + (t2 + t3);
            r2 = fmaf(t0, t0, r2); r2 = fmaf(t1, t1, r2);
            r2 = fmaf(t2, t2, r2); r2 = fmaf(t3, t3, r2);
            asm("v_cvt_pk_bf16_f32 %0, %1, %2" : "=v"(tp[2 * c]) : "v"(t0), "v"(t1));
            asm("v_cvt_pk_bf16_f32 %0, %1, %2" : "=v"(tp[2 * c + 1]) : "v"(t2), "v"(t3));
        }
    }
    r1 += __shfl_xor(r1, 1, 64);
    r2 += __shfl_xor(r2, 1, 64);
    float mean = r1 * (1.f / 128.f);
    float rstd = rsqrtf(r2 * (1.f / 128.f) - mean * mean + 1e-5f);
    float mr = mean * rstd;

    float dot = 0.f;
#pragma unroll
    for (int c = 0; c < 16; ++c) {
        float4 gv = *(const float4*)&lw[3][co + 4 * c];
        float4 bv = *(const float4*)&lw[4][co + 4 * c];
        float4 wv = *(const float4*)&lw[5][co + 4 * c];
        float t0 = bflo(tp[2 * c]), t1 = bfhi(tp[2 * c]);
        float t2 = bflo(tp[2 * c + 1]), t3 = bfhi(tp[2 * c + 1]);
        float h0 = fmaxf(fmaf(fmaf(t0, rstd, -mr), gv.x, bv.x), 0.f);
        float h1 = fmaxf(fmaf(fmaf(t1, rstd, -mr), gv.y, bv.y), 0.f);
        float h2 = fmaxf(fmaf(fmaf(t2, rstd, -mr), gv.z, bv.z), 0.f);
        float h3 = fmaxf(fmaf(fmaf(t3, rstd, -mr), gv.w, bv.w), 0.f);
        dot = fmaf(h0, wv.x, dot); dot = fmaf(h1, wv.y, dot);
        dot = fmaf(h2, wv.z, dot); dot = fmaf(h3, wv.w, dot);
    }
    dot += __shfl_xor(dot, 1, 64);
    if ((threadIdx.x & 1) == 0) wt[slot] = __expf(dot + ab2[0]);
}

// ---------------- aggregation: 8 lanes/node, 16 ch/lane; sums wt locally ----------------
// MODE 0: out = relu(xl + acc*ns); MODE 1: out = LN(xl + acc*ns; g,b)
template <int MODE>
__global__ __launch_bounds__(256) void aggr_kernel(
    const float* __restrict__ xl, const unsigned char* __restrict__ Vf8,
    const float* __restrict__ wt,
    const int* __restrict__ csr_src, const int* __restrict__ rowptr,
    const float* __restrict__ g, const float* __restrict__ b,
    float* __restrict__ out, int N) {
    const int lane8 = threadIdx.x & 7;
    const int v = blockIdx.x * 32 + ((int)threadIdx.x >> 3);
    if (v >= N) return;
    const int jb = lane8 * 16;

    const int s0 = rowptr[v], s1e = rowptr[v + 1];
    const int deg = s1e - s0;
    float acc[16];
#pragma unroll
    for (int k = 0; k < 16; ++k) acc[k] = 0.f;
    float wsum = 0.f;

    uint4 v0 = make_uint4(0, 0, 0, 0), v1 = v0;
    float wb0 = 0.f, wb1 = 0.f;
#define GATH2(idx, VV, WW)                                            \
    if ((idx) < s1e) {                                                \
        VV = *(const uint4*)(Vf8 + (size_t)csr_src[idx] * 128 + jb);  \
        WW = wt[idx];                                                 \
    }
    GATH2(s0, v0, wb0)
    GATH2(s0 + 1, v1, wb1)

    for (int i = s0; i < s1e; i += 2) {
        uint4 c0 = v0, c1 = v1;
        float u0 = wb0;
        float u1 = (i + 1 < s1e) ? wb1 : 0.f;
        GATH2(i + 2, v0, wb0)
        GATH2(i + 3, v1, wb1)
        wsum += u0 + u1;
        unsigned d0[4] = {c0.x, c0.y, c0.z, c0.w};
        unsigned d1[4] = {c1.x, c1.y, c1.z, c1.w};
#pragma unroll
        for (int k = 0; k < 4; ++k) {
            f32x2 alo = __builtin_amdgcn_cvt_pk_f32_fp8((int)d0[k], false);
            f32x2 ahi = __builtin_amdgcn_cvt_pk_f32_fp8((int)d0[k], true);
            f32x2 blo = __builtin_amdgcn_cvt_pk_f32_fp8((int)d1[k], false);
            f32x2 bhi = __builtin_amdgcn_cvt_pk_f32_fp8((int)d1[k], true);
            acc[4 * k + 0] += u0 * alo[0] + u1 * blo[0];
            acc[4 * k + 1] += u0 * alo[1] + u1 * blo[1];
            acc[4 * k + 2] += u0 * ahi[0] + u1 * bhi[0];
            acc[4 * k + 3] += u0 * ahi[1] + u1 * bhi[1];
        }
    }
#undef GATH2

    const float ns = (deg > 0) ? 1.f / (wsum * (float)deg) : 0.f;
    float o[16];
    const float* xp = xl + (size_t)v * 128 + jb;
#pragma unroll
    for (int k4 = 0; k4 < 4; ++k4) {
        float4 xa = *(const float4*)(xp + 4 * k4);
        o[4 * k4 + 0] = xa.x + acc[4 * k4 + 0] * ns;
        o[4 * k4 + 1] = xa.y + acc[4 * k4 + 1] * ns;
        o[4 * k4 + 2] = xa.z + acc[4 * k4 + 2] * ns;
        o[4 * k4 + 3] = xa.w + acc[4 * k4 + 3] * ns;
    }

    float* op = out + (size_t)v * 128 + jb;
    if (MODE == 0) {
#pragma unroll
        for (int k4 = 0; k4 < 4; ++k4) {
            float4 r;
            r.x = fmaxf(o[4 * k4 + 0], 0.f);
            r.y = fmaxf(o[4 * k4 + 1], 0.f);
            r.z = fmaxf(o[4 * k4 + 2], 0.f);
            r.w = fmaxf(o[4 * k4 + 3], 0.f);
            *(float4*)(op + 4 * k4) = r;
        }
    } else {
        float r1 = 0.f, r2 = 0.f;
#pragma unroll
        for (int k = 0; k < 16; ++k) { r1 += o[k]; r2 = fmaf(o[k], o[k], r2); }
#pragma unroll
        for (int mk = 4; mk >= 1; mk >>= 1) {
            r1 += __shfl_xor(r1, mk, 64);
            r2 += __shfl_xor(r2, mk, 64);
        }
        float mean = r1 * (1.f / 128.f);
        float rstd = rsqrtf(r2 * (1.f / 128.f) - mean * mean + 1e-5f);
        float mr = mean * rstd;
#pragma unroll
        for (int k4 = 0; k4 < 4; ++k4) {
            float4 gv = *(const float4*)(g + jb + 4 * k4);
            float4 bv = *(const float4*)(b + jb + 4 * k4);
            float4 r;
            r.x = fmaf(fmaf(o[4 * k4 + 0], rstd, -mr), gv.x, bv.x);
            r.y = fmaf(fmaf(o[4 * k4 + 1], rstd, -mr), gv.y, bv.y);
            r.z = fmaf(fmaf(o[4 * k4 + 2], rstd, -mr), gv.z, bv.z);
            r.w = fmaf(fmaf(o[4 * k4 + 3], rstd, -mr), gv.w, bv.w);
            *(float4*)(op + 4 * k4) = r;
        }
    }
}

// ---------------- pool stage 1: per-(graph, slice) partial max ----------------
__global__ __launch_bounds__(128) void pool1_kernel(const float* __restrict__ h,
                                                    const int* __restrict__ gstart,
                                                    const int* __restrict__ gend,
                                                    float* __restrict__ part) {
    int gph = blockIdx.x >> 4;
    int sl = blockIdx.x & 15;
    int col = threadIdx.x;
    int s = gstart[gph], e = gend[gph];
    float m = -INFINITY;
    for (int r = s + sl; r < e; r += 16) m = fmaxf(m, h[(size_t)r * 128 + col]);
    part[(size_t)blockIdx.x * 128 + col] = m;
}

// ---------------- classifier head (folds pool stage 2) ----------------
__global__ __launch_bounds__(128) void cls_kernel(const float* __restrict__ part,
                                                  const float* __restrict__ cw,
                                                  const float* __restrict__ cb,
                                                  float* __restrict__ out) {
    int gph = blockIdx.x, c = threadIdx.x;
    float m = -INFINITY;
#pragma unroll
    for (int sl = 0; sl < 16; ++sl) m = fmaxf(m, part[(size_t)(gph * 16 + sl) * 128 + c]);
    __shared__ float f[128];
    f[c] = m;
    __syncthreads();
    float acc = cb[c];
#pragma unroll 8
    for (int k = 0; k < 128; ++k) acc += f[k] * cw[k * 128 + c];
    out[gph * 128 + c] = acc;
}

// ---------------- launch ----------------
extern "C" void kernel_launch(void* const* d_in, const int* in_sizes, int n_in,
                              void* d_out, int out_size, void* d_ws, size_t ws_size,
                              hipStream_t stream) {
    const float* x      = (const float*)d_in[0];
    const int*   ei     = (const int*)d_in[1];
    const float* aux    = (const float*)d_in[2];
    const int*   batch  = (const int*)d_in[3];
    const float* w_lin1 = (const float*)d_in[4];
    const float* b_lin1 = (const float*)d_in[5];
    const float* aw1_1  = (const float*)d_in[6];
    const float* ab1_1  = (const float*)d_in[7];
    const float* lng1   = (const float*)d_in[8];
    const float* lnb1   = (const float*)d_in[9];
    const float* aw2_1  = (const float*)d_in[10];
    const float* ab2_1  = (const float*)d_in[11];
    const float* w_lin2 = (const float*)d_in[12];
    const float* b_lin2 = (const float*)d_in[13];
    const float* aw1_2  = (const float*)d_in[14];
    const float* ab1_2  = (const float*)d_in[15];
    const float* lng2   = (const float*)d_in[16];
    const float* lnb2   = (const float*)d_in[17];
    const float* aw2_2  = (const float*)d_in[18];
    const float* ab2_2  = (const float*)d_in[19];
    const float* cls_w  = (const float*)d_in[20];
    const float* cls_b  = (const float*)d_in[21];
    const float* norm_g = (const float*)d_in[22];
    const float* norm_b = (const float*)d_in[23];

    const int N = in_sizes[0] / 128;
    const int E = in_sizes[2] / 2;
    const int G = 64;
    const int* src = ei;
    const int* dst = ei + E;

    // workspace layout: 16B-aligned buffers first (all sizes multiples of 16B)
    char* wsp = (char*)d_ws;
    float*          xl    = (float*)wsp;            wsp += (size_t)N * 128 * 4;
    unsigned short* Qbf   = (unsigned short*)wsp;   wsp += (size_t)N * 128 * 2;
    unsigned char*  Pf8   = (unsigned char*)wsp;    wsp += (size_t)N * 128;
    unsigned char*  Vf8   = (unsigned char*)wsp;    wsp += (size_t)N * 128;
    unsigned short* wpack = (unsigned short*)wsp;   wsp += 6 * 16384 * 2;
    float*          part  = (float*)wsp;            wsp += (size_t)1024 * 128 * 4;
    float*          wt    = (float*)wsp;            wsp += (size_t)E * 4;
    float2*         aux2  = (float2*)wsp;           wsp += (size_t)E * 8;
    int*            deg     = (int*)wsp;            wsp += (size_t)N * 4;
    int*            cursor  = (int*)wsp;            wsp += (size_t)N * 4;
    int*            rowptr  = (int*)wsp;            wsp += (size_t)(N + 1) * 4;
    int*            csr_e   = (int*)wsp;            wsp += (size_t)E * 4;
    int*            csr_src = (int*)wsp;            wsp += (size_t)E * 4;
    int*            csr_dst = (int*)wsp;            wsp += (size_t)E * 4;
    int*            gstart  = (int*)wsp;            wsp += (size_t)G * 4;
    int*            gend    = (int*)wsp;            wsp += (size_t)G * 4;

    unsigned short* wp_lin1 = wpack;
    unsigned short* wp_s1   = wpack + 16384;
    unsigned short* wp_d1   = wpack + 2 * 16384;
    unsigned short* wp_lin2 = wpack + 3 * 16384;
    unsigned short* wp_s2   = wpack + 4 * 16384;
    unsigned short* wp_d2   = wpack + 5 * 16384;

    float* hout   = (float*)d_out;
    float* clsout = hout + (size_t)N * 128;

    hipMemsetAsync(deg, 0, (size_t)(2 * N) * sizeof(int), stream);      // deg + cursor
    hipMemsetAsync(gstart, 0, (size_t)(2 * G) * sizeof(int), stream);

    const int eb = (E + 255) / 256;
    const int nb = (N + 255) / 256;
    const int lb = (N + 31) / 32;
    const int atb = (E + 127) / 128;
    const int agb = (N + 31) / 32;

    hist_kernel<<<eb, 256, 0, stream>>>(dst, deg, E);
    scan_kernel<<<1, 1024, 0, stream>>>(deg, rowptr, N, E);
    scatter_kernel<<<eb, 256, 0, stream>>>(src, dst, aux, rowptr, cursor,
                                           csr_e, csr_src, csr_dst, aux2, E);
    sort_kernel<<<nb, 256, 0, stream>>>(csr_e, csr_src, aux2, rowptr, N);
    bounds_kernel<<<nb, 256, 0, stream>>>(batch, gstart, gend, N);

    pack6_kernel<<<384, 256, 0, stream>>>(w_lin1, aw1_1, aw1_1 + 128 * 128,
                                          w_lin2, aw1_2, aw1_2 + 128 * 128, wpack);

    // ---- conv1 ----
    linpq_kernel<<<lb, 256, 0, stream>>>(x, wp_lin1, b_lin1, wp_s1, wp_d1,
                                         xl, Vf8, Pf8, Qbf, N);
    attn_edge_kernel<<<atb, 256, 0, stream>>>(Pf8, Qbf, csr_src, csr_dst, aux2,
                                              aw1_1 + 256 * 128, aw1_1 + 257 * 128,
                                              ab1_1, lng1, lnb1, aw2_1, ab2_1, wt, E);
    aggr_kernel<0><<<agb, 256, 0, stream>>>(xl, Vf8, wt, csr_src, rowptr,
                                            nullptr, nullptr, hout, N);
    // ---- conv2 ----
    linpq_kernel<<<lb, 256, 0, stream>>>(hout, wp_lin2, b_lin2, wp_s2, wp_d2,
                                         xl, Vf8, Pf8, Qbf, N);
    attn_edge_kernel<<<atb, 256, 0, stream>>>(Pf8, Qbf, csr_src, csr_dst, aux2,
                                              aw1_2 + 256 * 128, aw1_2 + 257 * 128,
                                              ab1_2, lng2, lnb2, aw2_2, ab2_2, wt, E);
    aggr_kernel<1><<<agb, 256, 0, stream>>>(xl, Vf8, wt, csr_src, rowptr,
                                            norm_g, norm_b, hout, N);
    // ---- head ----
    pool1_kernel<<<G * 16, 128, 0, stream>>>(hout, gstart, gend, part);
    cls_kernel<<<G, 128, 0, stream>>>(part, cls_w, cls_b, clsout);
}

// Round 7
// 321.677 us; speedup vs baseline: 1.5085x; 1.1289x over previous
//
#include <hip/hip_runtime.h>
#include <math.h>

typedef __attribute__((ext_vector_type(8))) short short8v;   // 8 bf16 (4 VGPR)
typedef __attribute__((ext_vector_type(4))) float f32x4;
typedef __attribute__((ext_vector_type(2))) float f32x2;

// ---------------- helpers ----------------
__device__ __forceinline__ unsigned short f2bf(float f) {
    union { float f; unsigned int u; } v; v.f = f;
    unsigned int r = v.u + 0x7FFFu + ((v.u >> 16) & 1u);
    return (unsigned short)(r >> 16);
}
__device__ __forceinline__ float bflo(unsigned int v) {
    union { unsigned int u; float f; } x; x.u = v << 16; return x.f;
}
__device__ __forceinline__ float bfhi(unsigned int v) {
    union { unsigned int u; float f; } x; x.u = v & 0xFFFF0000u; return x.f;
}
__device__ __forceinline__ unsigned char f2fp8(float f) {
    return (unsigned char)(__builtin_amdgcn_cvt_pk_fp8_f32(f, f, 0, false) & 0xFF);
}

// ---------------- CSR build ----------------
__global__ void hist_kernel(const int* __restrict__ dst, int* __restrict__ deg, int E) {
    int e = blockIdx.x * 256 + threadIdx.x;
    if (e < E) atomicAdd(&deg[dst[e]], 1);
}

// stage 1: per-256-block exclusive scan + block total
__global__ __launch_bounds__(256) void scan1_kernel(const int* __restrict__ deg,
                                                    int* __restrict__ rp,
                                                    int* __restrict__ bsum, int N) {
    const int lane = threadIdx.x & 63, wid = threadIdx.x >> 6;
    int i = blockIdx.x * 256 + threadIdx.x;
    int v = (i < N) ? deg[i] : 0;
    int val = v;
#pragma unroll
    for (int off = 1; off < 64; off <<= 1) {
        int t = __shfl_up(val, off, 64);
        if (lane >= off) val += t;
    }
    __shared__ int ws[4];
    if (lane == 63) ws[wid] = val;
    __syncthreads();
    int pre = 0;
#pragma unroll
    for (int w = 0; w < 4; ++w) pre += (w < wid) ? ws[w] : 0;
    int incl = pre + val;
    if (i < N) rp[i] = incl - v;  // block-local exclusive
    if (threadIdx.x == 255) bsum[blockIdx.x] = incl;
}

// stage 2: single-block exclusive scan of block totals (NB <= 256)
__global__ __launch_bounds__(256) void scan2_kernel(int* __restrict__ bsum, int NB) {
    const int lane = threadIdx.x & 63, wid = threadIdx.x >> 6;
    int t = threadIdx.x;
    int v = (t < NB) ? bsum[t] : 0;
    int val = v;
#pragma unroll
    for (int off = 1; off < 64; off <<= 1) {
        int t2 = __shfl_up(val, off, 64);
        if (lane >= off) val += t2;
    }
    __shared__ int ws[4];
    if (lane == 63) ws[wid] = val;
    __syncthreads();
    int pre = 0;
#pragma unroll
    for (int w = 0; w < 4; ++w) pre += (w < wid) ? ws[w] : 0;
    int excl = pre + val - v;
    __syncthreads();
    if (t < NB) bsum[t] = excl;
}

// stage 3: add block offsets; set rowptr[N]=E
__global__ __launch_bounds__(256) void scan3_kernel(int* __restrict__ rp,
                                                    const int* __restrict__ bsum,
                                                    int N, int E) {
    int i = blockIdx.x * 256 + threadIdx.x;
    if (i < N) rp[i] += bsum[blockIdx.x];
    if (i == 0) rp[N] = E;
}

// scatter: one 16-B record per edge {eid, src, dst, aux bf16x2}
__global__ void scatter_kernel(const int* __restrict__ src, const int* __restrict__ dst,
                               const float* __restrict__ aux,
                               const int* __restrict__ rowptr, int* __restrict__ cursor,
                               uint4* __restrict__ er, int E) {
    int e = blockIdx.x * 256 + threadIdx.x;
    if (e < E) {
        int d = dst[e];
        int pos = rowptr[d] + atomicAdd(&cursor[d], 1);
        float2 a = *(const float2*)(aux + 2 * e);
        unsigned ap = (unsigned)f2bf(a.x) | ((unsigned)f2bf(a.y) << 16);
        uint4 r;
        r.x = (unsigned)e;
        r.y = (unsigned)src[e];
        r.z = (unsigned)d;
        r.w = ap;
        er[pos] = r;
    }
}

// deterministic order: sort each node's records by edge id; emit compact csr_src
__global__ void sort_kernel(uint4* __restrict__ er, const int* __restrict__ rowptr,
                            int* __restrict__ csr_src, int N) {
    int v = blockIdx.x * 256 + threadIdx.x;
    if (v >= N) return;
    int s = rowptr[v], e = rowptr[v + 1];
    for (int i = s + 1; i < e; ++i) {
        uint4 key = er[i];
        int kid = (int)key.x;
        int j = i - 1;
        while (j >= s && (int)er[j].x > kid) { er[j + 1] = er[j]; --j; }
        er[j + 1] = key;
    }
    for (int i = s; i < e; ++i) csr_src[i] = (int)er[i].y;
}

__global__ void bounds_kernel(const int* __restrict__ batch, int* __restrict__ gstart,
                              int* __restrict__ gend, int N) {
    int i = blockIdx.x * 256 + threadIdx.x;
    if (i >= N) return;
    int b = batch[i];
    if (i == 0 || batch[i - 1] != b) gstart[b] = i;
    if (i == N - 1 || batch[i + 1] != b) gend[b] = i + 1;
}

// ---------------- weight pack (6 matrices in one launch) ----------------
__global__ __launch_bounds__(256) void pack6_kernel(const float* __restrict__ s0,
                                                    const float* __restrict__ s1,
                                                    const float* __restrict__ s2,
                                                    const float* __restrict__ s3,
                                                    const float* __restrict__ s4,
                                                    const float* __restrict__ s5,
                                                    unsigned short* __restrict__ Wp) {
    int which = blockIdx.x >> 6;
    const float* W = (which == 0) ? s0 : (which == 1) ? s1 : (which == 2) ? s2
                   : (which == 3) ? s3 : (which == 4) ? s4 : s5;
    int t = (blockIdx.x & 63) * 256 + threadIdx.x;
    int j = t & 7, l = (t >> 3) & 63, ct = (t >> 9) & 7, ks = t >> 12;
    int k = ks * 32 + (l >> 4) * 8 + j;
    int n = ct * 16 + (l & 15);
    Wp[which * 16384 + t] = f2bf(W[k * 128 + n]);
}

// ---------------- fused MFMA GEMM: xl = A@WL + b; P = xl@WP; Q = xl@WQ ----------------
__global__ __launch_bounds__(256) void linpq_kernel(const float* __restrict__ A,
                                                    const unsigned short* __restrict__ WpL,
                                                    const float* __restrict__ bias,
                                                    const unsigned short* __restrict__ WpP,
                                                    const unsigned short* __restrict__ WpQ,
                                                    float* __restrict__ D,
                                                    unsigned char* __restrict__ Vf8,
                                                    unsigned char* __restrict__ Pf8,
                                                    unsigned short* __restrict__ Qbf, int M) {
    __shared__ unsigned short lds[32][136];  // +8 pad
    const int l = threadIdx.x & 63, w = threadIdx.x >> 6;
    const int tile = w >> 1, ch = w & 1;
    const int rowbase = blockIdx.x * 32 + tile * 16;
    const int r = rowbase + (l & 15);
    const int kc = (l >> 4) * 8;

    short8v afr[4];
    if (r < M) {
        const float* ap = A + (size_t)r * 128 + kc;
#pragma unroll
        for (int ks = 0; ks < 4; ++ks) {
            float4 x0 = *(const float4*)(ap + ks * 32);
            float4 x1 = *(const float4*)(ap + ks * 32 + 4);
            unsigned short u[8] = {f2bf(x0.x), f2bf(x0.y), f2bf(x0.z), f2bf(x0.w),
                                   f2bf(x1.x), f2bf(x1.y), f2bf(x1.z), f2bf(x1.w)};
            afr[ks] = *(short8v*)u;
        }
    } else {
#pragma unroll
        for (int ks = 0; ks < 4; ++ks)
#pragma unroll
            for (int j = 0; j < 8; ++j) afr[ks][j] = 0;
    }

    f32x4 acc[4];
#pragma unroll
    for (int c = 0; c < 4; ++c)
#pragma unroll
        for (int j = 0; j < 4; ++j) acc[c][j] = 0.f;

    const short8v* wl = (const short8v*)WpL;
#pragma unroll
    for (int ks = 0; ks < 4; ++ks)
#pragma unroll
        for (int c = 0; c < 4; ++c)
            acc[c] = __builtin_amdgcn_mfma_f32_16x16x32_bf16(
                afr[ks], wl[(ks * 8 + ch * 4 + c) * 64 + l], acc[c], 0, 0, 0);

    const int rb = rowbase + (l >> 4) * 4;
    const int lrb = tile * 16 + (l >> 4) * 4;
#pragma unroll
    for (int c = 0; c < 4; ++c) {
        int col = (ch * 4 + c) * 16 + (l & 15);
        float bv = bias ? bias[col] : 0.f;
#pragma unroll
        for (int j = 0; j < 4; ++j) {
            int row = rb + j;
            if (row < M) {
                float v = acc[c][j] + bv;
                unsigned short bf = f2bf(v);
                D[(size_t)row * 128 + col] = v;
                Vf8[(size_t)row * 128 + col] = f2fp8(v);
                lds[lrb + j][col] = bf;
            } else {
                lds[lrb + j][col] = 0;
            }
        }
    }
    __syncthreads();

    short8v xfr[4];
#pragma unroll
    for (int ks = 0; ks < 4; ++ks)
        xfr[ks] = *(const short8v*)&lds[tile * 16 + (l & 15)][kc + ks * 32];

    f32x4 accP[4], accQ[4];
#pragma unroll
    for (int c = 0; c < 4; ++c)
#pragma unroll
        for (int j = 0; j < 4; ++j) { accP[c][j] = 0.f; accQ[c][j] = 0.f; }

    const short8v* wp = (const short8v*)WpP;
    const short8v* wq = (const short8v*)WpQ;
#pragma unroll
    for (int ks = 0; ks < 4; ++ks)
#pragma unroll
        for (int c = 0; c < 4; ++c) {
            accP[c] = __builtin_amdgcn_mfma_f32_16x16x32_bf16(
                xfr[ks], wp[(ks * 8 + ch * 4 + c) * 64 + l], accP[c], 0, 0, 0);
            accQ[c] = __builtin_amdgcn_mfma_f32_16x16x32_bf16(
                xfr[ks], wq[(ks * 8 + ch * 4 + c) * 64 + l], accQ[c], 0, 0, 0);
        }

#pragma unroll
    for (int c = 0; c < 4; ++c) {
        int col = (ch * 4 + c) * 16 + (l & 15);
#pragma unroll
        for (int j = 0; j < 4; ++j) {
            int row = rb + j;
            if (row < M) {
                Pf8[(size_t)row * 128 + col] = f2fp8(accP[c][j]);
                Qbf[(size_t)row * 128 + col] = f2bf(accQ[c][j]);
            }
        }
    }
}

// ---------------- edge-parallel logits: 2 lanes/edge, 64 ch/lane ----------------
__global__ __launch_bounds__(256, 4) void attn_edge_kernel(
    const unsigned char* __restrict__ Pf8, const unsigned short* __restrict__ Qbf,
    const uint4* __restrict__ er,
    const float* __restrict__ wa0, const float* __restrict__ wa1,
    const float* __restrict__ ab1, const float* __restrict__ lng,
    const float* __restrict__ lnb, const float* __restrict__ aw2,
    const float* __restrict__ ab2,
    float* __restrict__ wt, int E) {
    __shared__ float lw[6][128];
    if (threadIdx.x < 128) {
        int c = threadIdx.x;
        lw[0][c] = wa0[c]; lw[1][c] = wa1[c]; lw[2][c] = ab1[c];
        lw[3][c] = lng[c]; lw[4][c] = lnb[c]; lw[5][c] = aw2[c];
    }
    __syncthreads();
    const int slot = blockIdx.x * 128 + ((int)threadIdx.x >> 1);
    if (slot >= E) return;
    const int co = (threadIdx.x & 1) << 6;  // channel offset: 0 or 64

    uint4 ev = er[slot];
    const int sn = (int)ev.y;
    const int dn = (int)ev.z;
    const float ax = bflo(ev.w), ay = bfhi(ev.w);

    const uint4* prow = (const uint4*)(Pf8 + (size_t)sn * 128 + co);
    const uint4* qrow = (const uint4*)(Qbf + ((size_t)dn * 128 + co));

    float r1 = 0.f, r2 = 0.f;
    unsigned tp[32];  // 64 ch as packed bf16

#pragma unroll
    for (int g = 0; g < 4; ++g) {  // 16 channels per group
        uint4 pv = prow[g];
        uint4 qa = qrow[2 * g];
        uint4 qb = qrow[2 * g + 1];
        unsigned pwa[4] = {pv.x, pv.y, pv.z, pv.w};
        unsigned qwa[8] = {qa.x, qa.y, qa.z, qa.w, qb.x, qb.y, qb.z, qb.w};
#pragma unroll
        for (int cc = 0; cc < 4; ++cc) {  // 4 channels
            const int c = g * 4 + cc;
            f32x2 plo = __builtin_amdgcn_cvt_pk_f32_fp8((int)pwa[cc], false);
            f32x2 phi = __builtin_amdgcn_cvt_pk_f32_fp8((int)pwa[cc], true);
            float4 w0v = *(const float4*)&lw[0][co + 4 * c];
            float4 w1v = *(const float4*)&lw[1][co + 4 * c];
            float4 b1v = *(const float4*)&lw[2][co + 4 * c];
            float q0 = bflo(qwa[2 * cc]), q1 = bfhi(qwa[2 * cc]);
            float q2 = bflo(qwa[2 * cc + 1]), q3 = bfhi(qwa[2 * cc + 1]);
            float t0 = plo[0] + q0 + ax * w0v.x + ay * w1v.x + b1v.x;
            float t1 = plo[1] + q1 + ax * w0v.y + ay * w1v.y + b1v.y;
            float t2 = phi[0] + q2 + ax * w0v.z + ay * w1v.z + b1v.z;
            float t3 = phi[1] + q3 + ax * w0v.w + ay * w1v.w + b1v.w;
            r1 += (t0 + t1) + (t2 + t3);
            r2 = fmaf(t0, t0, r2); r2 = fmaf(t1, t1, r2);
            r2 = fmaf(t2, t2, r2); r2 = fmaf(t3, t3, r2);
            asm("v_cvt_pk_bf16_f32 %0, %1, %2" : "=v"(tp[2 * c]) : "v"(t0), "v"(t1));
            asm("v_cvt_pk_bf16_f32 %0, %1, %2" : "=v"(tp[2 * c + 1]) : "v"(t2), "v"(t3));
        }
    }
    r1 += __shfl_xor(r1, 1, 64);
    r2 += __shfl_xor(r2, 1, 64);
    float mean = r1 * (1.f / 128.f);
    float rstd = rsqrtf(r2 * (1.f / 128.f) - mean * mean + 1e-5f);
    float mr = mean * rstd;

    float dot = 0.f;
#pragma unroll
    for (int c = 0; c < 16; ++c) {
        float4 gv = *(const float4*)&lw[3][co + 4 * c];
        float4 bv = *(const float4*)&lw[4][co + 4 * c];
        float4 wv = *(const float4*)&lw[5][co + 4 * c];
        float t0 = bflo(tp[2 * c]), t1 = bfhi(tp[2 * c]);
        float t2 = bflo(tp[2 * c + 1]), t3 = bfhi(tp[2 * c + 1]);
        float h0 = fmaxf(fmaf(fmaf(t0, rstd, -mr), gv.x, bv.x), 0.f);
        float h1 = fmaxf(fmaf(fmaf(t1, rstd, -mr), gv.y, bv.y), 0.f);
        float h2 = fmaxf(fmaf(fmaf(t2, rstd, -mr), gv.z, bv.z), 0.f);
        float h3 = fmaxf(fmaf(fmaf(t3, rstd, -mr), gv.w, bv.w), 0.f);
        dot = fmaf(h0, wv.x, dot); dot = fmaf(h1, wv.y, dot);
        dot = fmaf(h2, wv.z, dot); dot = fmaf(h3, wv.w, dot);
    }
    dot += __shfl_xor(dot, 1, 64);
    if ((threadIdx.x & 1) == 0) wt[slot] = __expf(dot + ab2[0]);
}

// ---------------- aggregation: 8 lanes/node, 16 ch/lane; sums wt locally ----------------
template <int MODE>
__global__ __launch_bounds__(256) void aggr_kernel(
    const float* __restrict__ xl, const unsigned char* __restrict__ Vf8,
    const float* __restrict__ wt,
    const int* __restrict__ csr_src, const int* __restrict__ rowptr,
    const float* __restrict__ g, const float* __restrict__ b,
    float* __restrict__ out, int N) {
    const int lane8 = threadIdx.x & 7;
    const int v = blockIdx.x * 32 + ((int)threadIdx.x >> 3);
    if (v >= N) return;
    const int jb = lane8 * 16;

    const int s0 = rowptr[v], s1e = rowptr[v + 1];
    const int deg = s1e - s0;
    float acc[16];
#pragma unroll
    for (int k = 0; k < 16; ++k) acc[k] = 0.f;
    float wsum = 0.f;

    uint4 v0 = make_uint4(0, 0, 0, 0), v1 = v0;
    float wb0 = 0.f, wb1 = 0.f;
#define GATH2(idx, VV, WW)                                            \
    if ((idx) < s1e) {                                                \
        VV = *(const uint4*)(Vf8 + (size_t)csr_src[idx] * 128 + jb);  \
        WW = wt[idx];                                                 \
    }
    GATH2(s0, v0, wb0)
    GATH2(s0 + 1, v1, wb1)

    for (int i = s0; i < s1e; i += 2) {
        uint4 c0 = v0, c1 = v1;
        float u0 = wb0;
        float u1 = (i + 1 < s1e) ? wb1 : 0.f;
        GATH2(i + 2, v0, wb0)
        GATH2(i + 3, v1, wb1)
        wsum += u0 + u1;
        unsigned d0[4] = {c0.x, c0.y, c0.z, c0.w};
        unsigned d1[4] = {c1.x, c1.y, c1.z, c1.w};
#pragma unroll
        for (int k = 0; k < 4; ++k) {
            f32x2 alo = __builtin_amdgcn_cvt_pk_f32_fp8((int)d0[k], false);
            f32x2 ahi = __builtin_amdgcn_cvt_pk_f32_fp8((int)d0[k], true);
            f32x2 blo = __builtin_amdgcn_cvt_pk_f32_fp8((int)d1[k], false);
            f32x2 bhi = __builtin_amdgcn_cvt_pk_f32_fp8((int)d1[k], true);
            acc[4 * k + 0] += u0 * alo[0] + u1 * blo[0];
            acc[4 * k + 1] += u0 * alo[1] + u1 * blo[1];
            acc[4 * k + 2] += u0 * ahi[0] + u1 * bhi[0];
            acc[4 * k + 3] += u0 * ahi[1] + u1 * bhi[1];
        }
    }
#undef GATH2

    const float ns = (deg > 0) ? 1.f / (wsum * (float)deg) : 0.f;
    float o[16];
    const float* xp = xl + (size_t)v * 128 + jb;
#pragma unroll
    for (int k4 = 0; k4 < 4; ++k4) {
        float4 xa = *(const float4*)(xp + 4 * k4);
        o[4 * k4 + 0] = xa.x + acc[4 * k4 + 0] * ns;
        o[4 * k4 + 1] = xa.y + acc[4 * k4 + 1] * ns;
        o[4 * k4 + 2] = xa.z + acc[4 * k4 + 2] * ns;
        o[4 * k4 + 3] = xa.w + acc[4 * k4 + 3] * ns;
    }

    float* op = out + (size_t)v * 128 + jb;
    if (MODE == 0) {
#pragma unroll
        for (int k4 = 0; k4 < 4; ++k4) {
            float4 r;
            r.x = fmaxf(o[4 * k4 + 0], 0.f);
            r.y = fmaxf(o[4 * k4 + 1], 0.f);
            r.z = fmaxf(o[4 * k4 + 2], 0.f);
            r.w = fmaxf(o[4 * k4 + 3], 0.f);
            *(float4*)(op + 4 * k4) = r;
        }
    } else {
        float r1 = 0.f, r2 = 0.f;
#pragma unroll
        for (int k = 0; k < 16; ++k) { r1 += o[k]; r2 = fmaf(o[k], o[k], r2); }
#pragma unroll
        for (int mk = 4; mk >= 1; mk >>= 1) {
            r1 += __shfl_xor(r1, mk, 64);
            r2 += __shfl_xor(r2, mk, 64);
        }
        float mean = r1 * (1.f / 128.f);
        float rstd = rsqrtf(r2 * (1.f / 128.f) - mean * mean + 1e-5f);
        float mr = mean * rstd;
#pragma unroll
        for (int k4 = 0; k4 < 4; ++k4) {
            float4 gv = *(const float4*)(g + jb + 4 * k4);
            float4 bv = *(const float4*)(b + jb + 4 * k4);
            float4 r;
            r.x = fmaf(fmaf(o[4 * k4 + 0], rstd, -mr), gv.x, bv.x);
            r.y = fmaf(fmaf(o[4 * k4 + 1], rstd, -mr), gv.y, bv.y);
            r.z = fmaf(fmaf(o[4 * k4 + 2], rstd, -mr), gv.z, bv.z);
            r.w = fmaf(fmaf(o[4 * k4 + 3], rstd, -mr), gv.w, bv.w);
            *(float4*)(op + 4 * k4) = r;
        }
    }
}

// ---------------- pool stage 1: per-(graph, slice) partial max ----------------
__global__ __launch_bounds__(128) void pool1_kernel(const float* __restrict__ h,
                                                    const int* __restrict__ gstart,
                                                    const int* __restrict__ gend,
                                                    float* __restrict__ part) {
    int gph = blockIdx.x >> 4;
    int sl = blockIdx.x & 15;
    int col = threadIdx.x;
    int s = gstart[gph], e = gend[gph];
    float m = -INFINITY;
    for (int r = s + sl; r < e; r += 16) m = fmaxf(m, h[(size_t)r * 128 + col]);
    part[(size_t)blockIdx.x * 128 + col] = m;
}

// ---------------- classifier head (folds pool stage 2) ----------------
__global__ __launch_bounds__(128) void cls_kernel(const float* __restrict__ part,
                                                  const float* __restrict__ cw,
                                                  const float* __restrict__ cb,
                                                  float* __restrict__ out) {
    int gph = blockIdx.x, c = threadIdx.x;
    float m = -INFINITY;
#pragma unroll
    for (int sl = 0; sl < 16; ++sl) m = fmaxf(m, part[(size_t)(gph * 16 + sl) * 128 + c]);
    __shared__ float f[128];
    f[c] = m;
    __syncthreads();
    float acc = cb[c];
#pragma unroll 8
    for (int k = 0; k < 128; ++k) acc += f[k] * cw[k * 128 + c];
    out[gph * 128 + c] = acc;
}

// ---------------- launch ----------------
extern "C" void kernel_launch(void* const* d_in, const int* in_sizes, int n_in,
                              void* d_out, int out_size, void* d_ws, size_t ws_size,
                              hipStream_t stream) {
    const float* x      = (const float*)d_in[0];
    const int*   ei     = (const int*)d_in[1];
    const float* aux    = (const float*)d_in[2];
    const int*   batch  = (const int*)d_in[3];
    const float* w_lin1 = (const float*)d_in[4];
    const float* b_lin1 = (const float*)d_in[5];
    const float* aw1_1  = (const float*)d_in[6];
    const float* ab1_1  = (const float*)d_in[7];
    const float* lng1   = (const float*)d_in[8];
    const float* lnb1   = (const float*)d_in[9];
    const float* aw2_1  = (const float*)d_in[10];
    const float* ab2_1  = (const float*)d_in[11];
    const float* w_lin2 = (const float*)d_in[12];
    const float* b_lin2 = (const float*)d_in[13];
    const float* aw1_2  = (const float*)d_in[14];
    const float* ab1_2  = (const float*)d_in[15];
    const float* lng2   = (const float*)d_in[16];
    const float* lnb2   = (const float*)d_in[17];
    const float* aw2_2  = (const float*)d_in[18];
    const float* ab2_2  = (const float*)d_in[19];
    const float* cls_w  = (const float*)d_in[20];
    const float* cls_b  = (const float*)d_in[21];
    const float* norm_g = (const float*)d_in[22];
    const float* norm_b = (const float*)d_in[23];

    const int N = in_sizes[0] / 128;
    const int E = in_sizes[2] / 2;
    const int G = 64;
    const int* src = ei;
    const int* dst = ei + E;

    // workspace layout: 16B-aligned buffers first
    char* wsp = (char*)d_ws;
    float*          xl    = (float*)wsp;            wsp += (size_t)N * 128 * 4;
    unsigned short* Qbf   = (unsigned short*)wsp;   wsp += (size_t)N * 128 * 2;
    unsigned char*  Pf8   = (unsigned char*)wsp;    wsp += (size_t)N * 128;
    unsigned char*  Vf8   = (unsigned char*)wsp;    wsp += (size_t)N * 128;
    unsigned short* wpack = (unsigned short*)wsp;   wsp += 6 * 16384 * 2;
    float*          part  = (float*)wsp;            wsp += (size_t)1024 * 128 * 4;
    uint4*          er    = (uint4*)wsp;            wsp += (size_t)E * 16;
    float*          wt    = (float*)wsp;            wsp += (size_t)E * 4;
    int*            bsum    = (int*)wsp;            wsp += 256 * 4;
    int*            deg     = (int*)wsp;            wsp += (size_t)N * 4;
    int*            cursor  = (int*)wsp;            wsp += (size_t)N * 4;
    int*            rowptr  = (int*)wsp;            wsp += (size_t)(N + 1) * 4;
    int*            csr_src = (int*)wsp;            wsp += (size_t)E * 4;
    int*            gstart  = (int*)wsp;            wsp += (size_t)G * 4;
    int*            gend    = (int*)wsp;            wsp += (size_t)G * 4;

    unsigned short* wp_lin1 = wpack;
    unsigned short* wp_s1   = wpack + 16384;
    unsigned short* wp_d1   = wpack + 2 * 16384;
    unsigned short* wp_lin2 = wpack + 3 * 16384;
    unsigned short* wp_s2   = wpack + 4 * 16384;
    unsigned short* wp_d2   = wpack + 5 * 16384;

    float* hout   = (float*)d_out;
    float* clsout = hout + (size_t)N * 128;

    hipMemsetAsync(deg, 0, (size_t)(2 * N) * sizeof(int), stream);      // deg + cursor
    hipMemsetAsync(gstart, 0, (size_t)(2 * G) * sizeof(int), stream);

    const int eb = (E + 255) / 256;
    const int nb = (N + 255) / 256;
    const int lb = (N + 31) / 32;
    const int atb = (E + 127) / 128;
    const int agb = (N + 31) / 32;

    hist_kernel<<<eb, 256, 0, stream>>>(dst, deg, E);
    scan1_kernel<<<nb, 256, 0, stream>>>(deg, rowptr, bsum, N);
    scan2_kernel<<<1, 256, 0, stream>>>(bsum, nb);
    scan3_kernel<<<nb, 256, 0, stream>>>(rowptr, bsum, N, E);
    scatter_kernel<<<eb, 256, 0, stream>>>(src, dst, aux, rowptr, cursor, er, E);
    sort_kernel<<<nb, 256, 0, stream>>>(er, rowptr, csr_src, N);
    bounds_kernel<<<nb, 256, 0, stream>>>(batch, gstart, gend, N);

    pack6_kernel<<<384, 256, 0, stream>>>(w_lin1, aw1_1, aw1_1 + 128 * 128,
                                          w_lin2, aw1_2, aw1_2 + 128 * 128, wpack);

    // ---- conv1 ----
    linpq_kernel<<<lb, 256, 0, stream>>>(x, wp_lin1, b_lin1, wp_s1, wp_d1,
                                         xl, Vf8, Pf8, Qbf, N);
    attn_edge_kernel<<<atb, 256, 0, stream>>>(Pf8, Qbf, er,
                                              aw1_1 + 256 * 128, aw1_1 + 257 * 128,
                                              ab1_1, lng1, lnb1, aw2_1, ab2_1, wt, E);
    aggr_kernel<0><<<agb, 256, 0, stream>>>(xl, Vf8, wt, csr_src, rowptr,
                                            nullptr, nullptr, hout, N);
    // ---- conv2 ----
    linpq_kernel<<<lb, 256, 0, stream>>>(hout, wp_lin2, b_lin2, wp_s2, wp_d2,
                                         xl, Vf8, Pf8, Qbf, N);
    attn_edge_kernel<<<atb, 256, 0, stream>>>(Pf8, Qbf, er,
                                              aw1_2 + 256 * 128, aw1_2 + 257 * 128,
                                              ab1_2, lng2, lnb2, aw2_2, ab2_2, wt, E);
    aggr_kernel<1><<<agb, 256, 0, stream>>>(xl, Vf8, wt, csr_src, rowptr,
                                            norm_g, norm_b, hout, N);
    // ---- head ----
    pool1_kernel<<<G * 16, 128, 0, stream>>>(hout, gstart, gend, part);
    cls_kernel<<<G, 128, 0, stream>>>(part, cls_w, cls_b, clsout);
}

// Round 8
// 269.895 us; speedup vs baseline: 1.7979x; 1.1919x over previous
//
#include <hip/hip_runtime.h>
#include <math.h>

typedef __attribute__((ext_vector_type(8))) short short8v;   // 8 bf16 (4 VGPR)
typedef __attribute__((ext_vector_type(4))) float f32x4;
typedef __attribute__((ext_vector_type(2))) float f32x2;

// ---------------- helpers ----------------
__device__ __forceinline__ unsigned short f2bf(float f) {
    union { float f; unsigned int u; } v; v.f = f;
    unsigned int r = v.u + 0x7FFFu + ((v.u >> 16) & 1u);
    return (unsigned short)(r >> 16);
}
__device__ __forceinline__ float bflo(unsigned int v) {
    union { unsigned int u; float f; } x; x.u = v << 16; return x.f;
}
__device__ __forceinline__ float bfhi(unsigned int v) {
    union { unsigned int u; float f; } x; x.u = v & 0xFFFF0000u; return x.f;
}
__device__ __forceinline__ unsigned char f2fp8(float f) {
    return (unsigned char)(__builtin_amdgcn_cvt_pk_fp8_f32(f, f, 0, false) & 0xFF);
}

// ---------------- CSR build ----------------
__global__ void hist_kernel(const int* __restrict__ dst, int* __restrict__ deg, int E) {
    int e = blockIdx.x * 256 + threadIdx.x;
    if (e < E) atomicAdd(&deg[dst[e]], 1);
}

// stage 1: per-256-block exclusive scan + block total
__global__ __launch_bounds__(256) void scan1_kernel(const int* __restrict__ deg,
                                                    int* __restrict__ rp,
                                                    int* __restrict__ bsum, int N) {
    const int lane = threadIdx.x & 63, wid = threadIdx.x >> 6;
    int i = blockIdx.x * 256 + threadIdx.x;
    int v = (i < N) ? deg[i] : 0;
    int val = v;
#pragma unroll
    for (int off = 1; off < 64; off <<= 1) {
        int t = __shfl_up(val, off, 64);
        if (lane >= off) val += t;
    }
    __shared__ int ws[4];
    if (lane == 63) ws[wid] = val;
    __syncthreads();
    int pre = 0;
#pragma unroll
    for (int w = 0; w < 4; ++w) pre += (w < wid) ? ws[w] : 0;
    int incl = pre + val;
    if (i < N) rp[i] = incl - v;  // block-local exclusive
    if (threadIdx.x == 255) bsum[blockIdx.x] = incl;
}

// stage 2: single-block exclusive scan of block totals (NB <= 256)
__global__ __launch_bounds__(256) void scan2_kernel(int* __restrict__ bsum, int NB) {
    const int lane = threadIdx.x & 63, wid = threadIdx.x >> 6;
    int t = threadIdx.x;
    int v = (t < NB) ? bsum[t] : 0;
    int val = v;
#pragma unroll
    for (int off = 1; off < 64; off <<= 1) {
        int t2 = __shfl_up(val, off, 64);
        if (lane >= off) val += t2;
    }
    __shared__ int ws[4];
    if (lane == 63) ws[wid] = val;
    __syncthreads();
    int pre = 0;
#pragma unroll
    for (int w = 0; w < 4; ++w) pre += (w < wid) ? ws[w] : 0;
    int excl = pre + val - v;
    __syncthreads();
    if (t < NB) bsum[t] = excl;
}

// stage 3: add block offsets; set rowptr[N]=E
__global__ __launch_bounds__(256) void scan3_kernel(int* __restrict__ rp,
                                                    const int* __restrict__ bsum,
                                                    int N, int E) {
    int i = blockIdx.x * 256 + threadIdx.x;
    if (i < N) rp[i] += bsum[blockIdx.x];
    if (i == 0) rp[N] = E;
}

// scatter: one 8-B record per edge {src | dst<<16, aux bf16x2}  (N < 65536)
// NOTE: slot order within a dst segment follows atomic arrival order — softmax
// and mean are order-invariant up to fp rounding (~1e-6 << 0.1 threshold).
__global__ void scatter_kernel(const int* __restrict__ src, const int* __restrict__ dst,
                               const float* __restrict__ aux,
                               const int* __restrict__ rowptr, int* __restrict__ cursor,
                               uint2* __restrict__ er, int E) {
    int e = blockIdx.x * 256 + threadIdx.x;
    if (e < E) {
        int d = dst[e];
        int pos = rowptr[d] + atomicAdd(&cursor[d], 1);
        float2 a = *(const float2*)(aux + 2 * e);
        uint2 r;
        r.x = (unsigned)src[e] | ((unsigned)d << 16);
        r.y = (unsigned)f2bf(a.x) | ((unsigned)f2bf(a.y) << 16);
        er[pos] = r;
    }
}

__global__ void bounds_kernel(const int* __restrict__ batch, int* __restrict__ gstart,
                              int* __restrict__ gend, int N) {
    int i = blockIdx.x * 256 + threadIdx.x;
    if (i >= N) return;
    int b = batch[i];
    if (i == 0 || batch[i - 1] != b) gstart[b] = i;
    if (i == N - 1 || batch[i + 1] != b) gend[b] = i + 1;
}

// ---------------- weight pack (6 matrices in one launch) ----------------
__global__ __launch_bounds__(256) void pack6_kernel(const float* __restrict__ s0,
                                                    const float* __restrict__ s1,
                                                    const float* __restrict__ s2,
                                                    const float* __restrict__ s3,
                                                    const float* __restrict__ s4,
                                                    const float* __restrict__ s5,
                                                    unsigned short* __restrict__ Wp) {
    int which = blockIdx.x >> 6;
    const float* W = (which == 0) ? s0 : (which == 1) ? s1 : (which == 2) ? s2
                   : (which == 3) ? s3 : (which == 4) ? s4 : s5;
    int t = (blockIdx.x & 63) * 256 + threadIdx.x;
    int j = t & 7, l = (t >> 3) & 63, ct = (t >> 9) & 7, ks = t >> 12;
    int k = ks * 32 + (l >> 4) * 8 + j;
    int n = ct * 16 + (l & 15);
    Wp[which * 16384 + t] = f2bf(W[k * 128 + n]);
}

// ---------------- fused MFMA GEMM: xl = A@WL + b; P = xl@WP; Q = xl@WQ ----------------
__global__ __launch_bounds__(256) void linpq_kernel(const float* __restrict__ A,
                                                    const unsigned short* __restrict__ WpL,
                                                    const float* __restrict__ bias,
                                                    const unsigned short* __restrict__ WpP,
                                                    const unsigned short* __restrict__ WpQ,
                                                    float* __restrict__ D,
                                                    unsigned char* __restrict__ Vf8,
                                                    unsigned char* __restrict__ Pf8,
                                                    unsigned short* __restrict__ Qbf, int M) {
    __shared__ unsigned short lds[32][136];  // +8 pad
    const int l = threadIdx.x & 63, w = threadIdx.x >> 6;
    const int tile = w >> 1, ch = w & 1;
    const int rowbase = blockIdx.x * 32 + tile * 16;
    const int r = rowbase + (l & 15);
    const int kc = (l >> 4) * 8;

    short8v afr[4];
    if (r < M) {
        const float* ap = A + (size_t)r * 128 + kc;
#pragma unroll
        for (int ks = 0; ks < 4; ++ks) {
            float4 x0 = *(const float4*)(ap + ks * 32);
            float4 x1 = *(const float4*)(ap + ks * 32 + 4);
            unsigned short u[8] = {f2bf(x0.x), f2bf(x0.y), f2bf(x0.z), f2bf(x0.w),
                                   f2bf(x1.x), f2bf(x1.y), f2bf(x1.z), f2bf(x1.w)};
            afr[ks] = *(short8v*)u;
        }
    } else {
#pragma unroll
        for (int ks = 0; ks < 4; ++ks)
#pragma unroll
            for (int j = 0; j < 8; ++j) afr[ks][j] = 0;
    }

    f32x4 acc[4];
#pragma unroll
    for (int c = 0; c < 4; ++c)
#pragma unroll
        for (int j = 0; j < 4; ++j) acc[c][j] = 0.f;

    const short8v* wl = (const short8v*)WpL;
#pragma unroll
    for (int ks = 0; ks < 4; ++ks)
#pragma unroll
        for (int c = 0; c < 4; ++c)
            acc[c] = __builtin_amdgcn_mfma_f32_16x16x32_bf16(
                afr[ks], wl[(ks * 8 + ch * 4 + c) * 64 + l], acc[c], 0, 0, 0);

    const int rb = rowbase + (l >> 4) * 4;
    const int lrb = tile * 16 + (l >> 4) * 4;
#pragma unroll
    for (int c = 0; c < 4; ++c) {
        int col = (ch * 4 + c) * 16 + (l & 15);
        float bv = bias ? bias[col] : 0.f;
#pragma unroll
        for (int j = 0; j < 4; ++j) {
            int row = rb + j;
            if (row < M) {
                float v = acc[c][j] + bv;
                unsigned short bf = f2bf(v);
                D[(size_t)row * 128 + col] = v;
                Vf8[(size_t)row * 128 + col] = f2fp8(v);
                lds[lrb + j][col] = bf;
            } else {
                lds[lrb + j][col] = 0;
            }
        }
    }
    __syncthreads();

    short8v xfr[4];
#pragma unroll
    for (int ks = 0; ks < 4; ++ks)
        xfr[ks] = *(const short8v*)&lds[tile * 16 + (l & 15)][kc + ks * 32];

    f32x4 accP[4], accQ[4];
#pragma unroll
    for (int c = 0; c < 4; ++c)
#pragma unroll
        for (int j = 0; j < 4; ++j) { accP[c][j] = 0.f; accQ[c][j] = 0.f; }

    const short8v* wp = (const short8v*)WpP;
    const short8v* wq = (const short8v*)WpQ;
#pragma unroll
    for (int ks = 0; ks < 4; ++ks)
#pragma unroll
        for (int c = 0; c < 4; ++c) {
            accP[c] = __builtin_amdgcn_mfma_f32_16x16x32_bf16(
                xfr[ks], wp[(ks * 8 + ch * 4 + c) * 64 + l], accP[c], 0, 0, 0);
            accQ[c] = __builtin_amdgcn_mfma_f32_16x16x32_bf16(
                xfr[ks], wq[(ks * 8 + ch * 4 + c) * 64 + l], accQ[c], 0, 0, 0);
        }

#pragma unroll
    for (int c = 0; c < 4; ++c) {
        int col = (ch * 4 + c) * 16 + (l & 15);
#pragma unroll
        for (int j = 0; j < 4; ++j) {
            int row = rb + j;
            if (row < M) {
                Pf8[(size_t)row * 128 + col] = f2fp8(accP[c][j]);
                Qbf[(size_t)row * 128 + col] = f2bf(accQ[c][j]);
            }
        }
    }
}

// ---------------- edge-parallel logits: 2 lanes/edge, 64 ch/lane ----------------
__global__ __launch_bounds__(256, 4) void attn_edge_kernel(
    const unsigned char* __restrict__ Pf8, const unsigned short* __restrict__ Qbf,
    const uint2* __restrict__ er,
    const float* __restrict__ wa0, const float* __restrict__ wa1,
    const float* __restrict__ ab1, const float* __restrict__ lng,
    const float* __restrict__ lnb, const float* __restrict__ aw2,
    const float* __restrict__ ab2,
    float* __restrict__ wt, int E) {
    __shared__ float lw[6][128];
    if (threadIdx.x < 128) {
        int c = threadIdx.x;
        lw[0][c] = wa0[c]; lw[1][c] = wa1[c]; lw[2][c] = ab1[c];
        lw[3][c] = lng[c]; lw[4][c] = lnb[c]; lw[5][c] = aw2[c];
    }
    __syncthreads();
    const int slot = blockIdx.x * 128 + ((int)threadIdx.x >> 1);
    if (slot >= E) return;
    const int co = (threadIdx.x & 1) << 6;  // channel offset: 0 or 64

    uint2 ev = er[slot];
    const int sn = (int)(ev.x & 0xFFFFu);
    const int dn = (int)(ev.x >> 16);
    const float ax = bflo(ev.y), ay = bfhi(ev.y);

    const uint4* prow = (const uint4*)(Pf8 + (size_t)sn * 128 + co);
    const uint4* qrow = (const uint4*)(Qbf + ((size_t)dn * 128 + co));

    float r1 = 0.f, r2 = 0.f;
    unsigned tp[32];  // 64 ch as packed bf16

#pragma unroll
    for (int g = 0; g < 4; ++g) {  // 16 channels per group
        uint4 pv = prow[g];
        uint4 qa = qrow[2 * g];
        uint4 qb = qrow[2 * g + 1];
        unsigned pwa[4] = {pv.x, pv.y, pv.z, pv.w};
        unsigned qwa[8] = {qa.x, qa.y, qa.z, qa.w, qb.x, qb.y, qb.z, qb.w};
#pragma unroll
        for (int cc = 0; cc < 4; ++cc) {  // 4 channels
            const int c = g * 4 + cc;
            f32x2 plo = __builtin_amdgcn_cvt_pk_f32_fp8((int)pwa[cc], false);
            f32x2 phi = __builtin_amdgcn_cvt_pk_f32_fp8((int)pwa[cc], true);
            float4 w0v = *(const float4*)&lw[0][co + 4 * c];
            float4 w1v = *(const float4*)&lw[1][co + 4 * c];
            float4 b1v = *(const float4*)&lw[2][co + 4 * c];
            float q0 = bflo(qwa[2 * cc]), q1 = bfhi(qwa[2 * cc]);
            float q2 = bflo(qwa[2 * cc + 1]), q3 = bfhi(qwa[2 * cc + 1]);
            float t0 = plo[0] + q0 + ax * w0v.x + ay * w1v.x + b1v.x;
            float t1 = plo[1] + q1 + ax * w0v.y + ay * w1v.y + b1v.y;
            float t2 = phi[0] + q2 + ax * w0v.z + ay * w1v.z + b1v.z;
            float t3 = phi[1] + q3 + ax * w0v.w + ay * w1v.w + b1v.w;
            r1 += (t0 + t1) + (t2 + t3);
            r2 = fmaf(t0, t0, r2); r2 = fmaf(t1, t1, r2);
            r2 = fmaf(t2, t2, r2); r2 = fmaf(t3, t3, r2);
            asm("v_cvt_pk_bf16_f32 %0, %1, %2" : "=v"(tp[2 * c]) : "v"(t0), "v"(t1));
            asm("v_cvt_pk_bf16_f32 %0, %1, %2" : "=v"(tp[2 * c + 1]) : "v"(t2), "v"(t3));
        }
    }
    r1 += __shfl_xor(r1, 1, 64);
    r2 += __shfl_xor(r2, 1, 64);
    float mean = r1 * (1.f / 128.f);
    float rstd = rsqrtf(r2 * (1.f / 128.f) - mean * mean + 1e-5f);
    float mr = mean * rstd;

    float dot = 0.f;
#pragma unroll
    for (int c = 0; c < 16; ++c) {
        float4 gv = *(const float4*)&lw[3][co + 4 * c];
        float4 bv = *(const float4*)&lw[4][co + 4 * c];
        float4 wv = *(const float4*)&lw[5][co + 4 * c];
        float t0 = bflo(tp[2 * c]), t1 = bfhi(tp[2 * c]);
        float t2 = bflo(tp[2 * c + 1]), t3 = bfhi(tp[2 * c + 1]);
        float h0 = fmaxf(fmaf(fmaf(t0, rstd, -mr), gv.x, bv.x), 0.f);
        float h1 = fmaxf(fmaf(fmaf(t1, rstd, -mr), gv.y, bv.y), 0.f);
        float h2 = fmaxf(fmaf(fmaf(t2, rstd, -mr), gv.z, bv.z), 0.f);
        float h3 = fmaxf(fmaf(fmaf(t3, rstd, -mr), gv.w, bv.w), 0.f);
        dot = fmaf(h0, wv.x, dot); dot = fmaf(h1, wv.y, dot);
        dot = fmaf(h2, wv.z, dot); dot = fmaf(h3, wv.w, dot);
    }
    dot += __shfl_xor(dot, 1, 64);
    if ((threadIdx.x & 1) == 0) wt[slot] = __expf(dot + ab2[0]);
}

// ---------------- aggregation: 8 lanes/node, 16 ch/lane; sums wt locally ----------------
template <int MODE>
__global__ __launch_bounds__(256) void aggr_kernel(
    const float* __restrict__ xl, const unsigned char* __restrict__ Vf8,
    const float* __restrict__ wt,
    const uint2* __restrict__ er, const int* __restrict__ rowptr,
    const float* __restrict__ g, const float* __restrict__ b,
    float* __restrict__ out, int N) {
    const int lane8 = threadIdx.x & 7;
    const int v = blockIdx.x * 32 + ((int)threadIdx.x >> 3);
    if (v >= N) return;
    const int jb = lane8 * 16;

    const int s0 = rowptr[v], s1e = rowptr[v + 1];
    const int deg = s1e - s0;
    float acc[16];
#pragma unroll
    for (int k = 0; k < 16; ++k) acc[k] = 0.f;
    float wsum = 0.f;

    uint4 v0 = make_uint4(0, 0, 0, 0), v1 = v0;
    float wb0 = 0.f, wb1 = 0.f;
#define GATH2(idx, VV, WW)                                                       \
    if ((idx) < s1e) {                                                           \
        int sn_ = (int)(er[idx].x & 0xFFFFu);                                    \
        VV = *(const uint4*)(Vf8 + (size_t)sn_ * 128 + jb);                      \
        WW = wt[idx];                                                            \
    }
    GATH2(s0, v0, wb0)
    GATH2(s0 + 1, v1, wb1)

    for (int i = s0; i < s1e; i += 2) {
        uint4 c0 = v0, c1 = v1;
        float u0 = wb0;
        float u1 = (i + 1 < s1e) ? wb1 : 0.f;
        GATH2(i + 2, v0, wb0)
        GATH2(i + 3, v1, wb1)
        wsum += u0 + u1;
        unsigned d0[4] = {c0.x, c0.y, c0.z, c0.w};
        unsigned d1[4] = {c1.x, c1.y, c1.z, c1.w};
#pragma unroll
        for (int k = 0; k < 4; ++k) {
            f32x2 alo = __builtin_amdgcn_cvt_pk_f32_fp8((int)d0[k], false);
            f32x2 ahi = __builtin_amdgcn_cvt_pk_f32_fp8((int)d0[k], true);
            f32x2 blo = __builtin_amdgcn_cvt_pk_f32_fp8((int)d1[k], false);
            f32x2 bhi = __builtin_amdgcn_cvt_pk_f32_fp8((int)d1[k], true);
            acc[4 * k + 0] += u0 * alo[0] + u1 * blo[0];
            acc[4 * k + 1] += u0 * alo[1] + u1 * blo[1];
            acc[4 * k + 2] += u0 * ahi[0] + u1 * bhi[0];
            acc[4 * k + 3] += u0 * ahi[1] + u1 * bhi[1];
        }
    }
#undef GATH2

    const float ns = (deg > 0) ? 1.f / (wsum * (float)deg) : 0.f;
    float o[16];
    const float* xp = xl + (size_t)v * 128 + jb;
#pragma unroll
    for (int k4 = 0; k4 < 4; ++k4) {
        float4 xa = *(const float4*)(xp + 4 * k4);
        o[4 * k4 + 0] = xa.x + acc[4 * k4 + 0] * ns;
        o[4 * k4 + 1] = xa.y + acc[4 * k4 + 1] * ns;
        o[4 * k4 + 2] = xa.z + acc[4 * k4 + 2] * ns;
        o[4 * k4 + 3] = xa.w + acc[4 * k4 + 3] * ns;
    }

    float* op = out + (size_t)v * 128 + jb;
    if (MODE == 0) {
#pragma unroll
        for (int k4 = 0; k4 < 4; ++k4) {
            float4 r;
            r.x = fmaxf(o[4 * k4 + 0], 0.f);
            r.y = fmaxf(o[4 * k4 + 1], 0.f);
            r.z = fmaxf(o[4 * k4 + 2], 0.f);
            r.w = fmaxf(o[4 * k4 + 3], 0.f);
            *(float4*)(op + 4 * k4) = r;
        }
    } else {
        float r1 = 0.f, r2 = 0.f;
#pragma unroll
        for (int k = 0; k < 16; ++k) { r1 += o[k]; r2 = fmaf(o[k], o[k], r2); }
#pragma unroll
        for (int mk = 4; mk >= 1; mk >>= 1) {
            r1 += __shfl_xor(r1, mk, 64);
            r2 += __shfl_xor(r2, mk, 64);
        }
        float mean = r1 * (1.f / 128.f);
        float rstd = rsqrtf(r2 * (1.f / 128.f) - mean * mean + 1e-5f);
        float mr = mean * rstd;
#pragma unroll
        for (int k4 = 0; k4 < 4; ++k4) {
            float4 gv = *(const float4*)(g + jb + 4 * k4);
            float4 bv = *(const float4*)(b + jb + 4 * k4);
            float4 r;
            r.x = fmaf(fmaf(o[4 * k4 + 0], rstd, -mr), gv.x, bv.x);
            r.y = fmaf(fmaf(o[4 * k4 + 1], rstd, -mr), gv.y, bv.y);
            r.z = fmaf(fmaf(o[4 * k4 + 2], rstd, -mr), gv.z, bv.z);
            r.w = fmaf(fmaf(o[4 * k4 + 3], rstd, -mr), gv.w, bv.w);
            *(float4*)(op + 4 * k4) = r;
        }
    }
}

// ---------------- pool stage 1: per-(graph, slice) partial max ----------------
__global__ __launch_bounds__(128) void pool1_kernel(const float* __restrict__ h,
                                                    const int* __restrict__ gstart,
                                                    const int* __restrict__ gend,
                                                    float* __restrict__ part) {
    int gph = blockIdx.x >> 4;
    int sl = blockIdx.x & 15;
    int col = threadIdx.x;
    int s = gstart[gph], e = gend[gph];
    float m = -INFINITY;
    for (int r = s + sl; r < e; r += 16) m = fmaxf(m, h[(size_t)r * 128 + col]);
    part[(size_t)blockIdx.x * 128 + col] = m;
}

// ---------------- classifier head (folds pool stage 2) ----------------
__global__ __launch_bounds__(128) void cls_kernel(const float* __restrict__ part,
                                                  const float* __restrict__ cw,
                                                  const float* __restrict__ cb,
                                                  float* __restrict__ out) {
    int gph = blockIdx.x, c = threadIdx.x;
    float m = -INFINITY;
#pragma unroll
    for (int sl = 0; sl < 16; ++sl) m = fmaxf(m, part[(size_t)(gph * 16 + sl) * 128 + c]);
    __shared__ float f[128];
    f[c] = m;
    __syncthreads();
    float acc = cb[c];
#pragma unroll 8
    for (int k = 0; k < 128; ++k) acc += f[k] * cw[k * 128 + c];
    out[gph * 128 + c] = acc;
}

// ---------------- launch ----------------
extern "C" void kernel_launch(void* const* d_in, const int* in_sizes, int n_in,
                              void* d_out, int out_size, void* d_ws, size_t ws_size,
                              hipStream_t stream) {
    const float* x      = (const float*)d_in[0];
    const int*   ei     = (const int*)d_in[1];
    const float* aux    = (const float*)d_in[2];
    const int*   batch  = (const int*)d_in[3];
    const float* w_lin1 = (const float*)d_in[4];
    const float* b_lin1 = (const float*)d_in[5];
    const float* aw1_1  = (const float*)d_in[6];
    const float* ab1_1  = (const float*)d_in[7];
    const float* lng1   = (const float*)d_in[8];
    const float* lnb1   = (const float*)d_in[9];
    const float* aw2_1  = (const float*)d_in[10];
    const float* ab2_1  = (const float*)d_in[11];
    const float* w_lin2 = (const float*)d_in[12];
    const float* b_lin2 = (const float*)d_in[13];
    const float* aw1_2  = (const float*)d_in[14];
    const float* ab1_2  = (const float*)d_in[15];
    const float* lng2   = (const float*)d_in[16];
    const float* lnb2   = (const float*)d_in[17];
    const float* aw2_2  = (const float*)d_in[18];
    const float* ab2_2  = (const float*)d_in[19];
    const float* cls_w  = (const float*)d_in[20];
    const float* cls_b  = (const float*)d_in[21];
    const float* norm_g = (const float*)d_in[22];
    const float* norm_b = (const float*)d_in[23];

    const int N = in_sizes[0] / 128;
    const int E = in_sizes[2] / 2;
    const int G = 64;
    const int* src = ei;
    const int* dst = ei + E;

    // workspace layout: 16B-aligned buffers first
    char* wsp = (char*)d_ws;
    float*          xl    = (float*)wsp;            wsp += (size_t)N * 128 * 4;
    unsigned short* Qbf   = (unsigned short*)wsp;   wsp += (size_t)N * 128 * 2;
    unsigned char*  Pf8   = (unsigned char*)wsp;    wsp += (size_t)N * 128;
    unsigned char*  Vf8   = (unsigned char*)wsp;    wsp += (size_t)N * 128;
    unsigned short* wpack = (unsigned short*)wsp;   wsp += 6 * 16384 * 2;
    float*          part  = (float*)wsp;            wsp += (size_t)1024 * 128 * 4;
    uint2*          er    = (uint2*)wsp;            wsp += (size_t)E * 8;
    float*          wt    = (float*)wsp;            wsp += (size_t)E * 4;
    int*            bsum    = (int*)wsp;            wsp += 256 * 4;
    int*            deg     = (int*)wsp;            wsp += (size_t)N * 4;
    int*            cursor  = (int*)wsp;            wsp += (size_t)N * 4;
    int*            rowptr  = (int*)wsp;            wsp += (size_t)(N + 1) * 4;
    int*            gstart  = (int*)wsp;            wsp += (size_t)G * 4;
    int*            gend    = (int*)wsp;            wsp += (size_t)G * 4;

    unsigned short* wp_lin1 = wpack;
    unsigned short* wp_s1   = wpack + 16384;
    unsigned short* wp_d1   = wpack + 2 * 16384;
    unsigned short* wp_lin2 = wpack + 3 * 16384;
    unsigned short* wp_s2   = wpack + 4 * 16384;
    unsigned short* wp_d2   = wpack + 5 * 16384;

    float* hout   = (float*)d_out;
    float* clsout = hout + (size_t)N * 128;

    hipMemsetAsync(deg, 0, (size_t)(2 * N) * sizeof(int), stream);      // deg + cursor
    hipMemsetAsync(gstart, 0, (size_t)(2 * G) * sizeof(int), stream);

    const int eb = (E + 255) / 256;
    const int nb = (N + 255) / 256;
    const int lb = (N + 31) / 32;
    const int atb = (E + 127) / 128;
    const int agb = (N + 31) / 32;

    hist_kernel<<<eb, 256, 0, stream>>>(dst, deg, E);
    scan1_kernel<<<nb, 256, 0, stream>>>(deg, rowptr, bsum, N);
    scan2_kernel<<<1, 256, 0, stream>>>(bsum, nb);
    scan3_kernel<<<nb, 256, 0, stream>>>(rowptr, bsum, N, E);
    scatter_kernel<<<eb, 256, 0, stream>>>(src, dst, aux, rowptr, cursor, er, E);
    bounds_kernel<<<nb, 256, 0, stream>>>(batch, gstart, gend, N);

    pack6_kernel<<<384, 256, 0, stream>>>(w_lin1, aw1_1, aw1_1 + 128 * 128,
                                          w_lin2, aw1_2, aw1_2 + 128 * 128, wpack);

    // ---- conv1 ----
    linpq_kernel<<<lb, 256, 0, stream>>>(x, wp_lin1, b_lin1, wp_s1, wp_d1,
                                         xl, Vf8, Pf8, Qbf, N);
    attn_edge_kernel<<<atb, 256, 0, stream>>>(Pf8, Qbf, er,
                                              aw1_1 + 256 * 128, aw1_1 + 257 * 128,
                                              ab1_1, lng1, lnb1, aw2_1, ab2_1, wt, E);
    aggr_kernel<0><<<agb, 256, 0, stream>>>(xl, Vf8, wt, er, rowptr,
                                            nullptr, nullptr, hout, N);
    // ---- conv2 ----
    linpq_kernel<<<lb, 256, 0, stream>>>(hout, wp_lin2, b_lin2, wp_s2, wp_d2,
                                         xl, Vf8, Pf8, Qbf, N);
    attn_edge_kernel<<<atb, 256, 0, stream>>>(Pf8, Qbf, er,
                                              aw1_2 + 256 * 128, aw1_2 + 257 * 128,
                                              ab1_2, lng2, lnb2, aw2_2, ab2_2, wt, E);
    aggr_kernel<1><<<agb, 256, 0, stream>>>(xl, Vf8, wt, er, rowptr,
                                            norm_g, norm_b, hout, N);
    // ---- head ----
    pool1_kernel<<<G * 16, 128, 0, stream>>>(hout, gstart, gend, part);
    cls_kernel<<<G, 128, 0, stream>>>(part, cls_w, cls_b, clsout);
}